// Round 6
// baseline (3214.017 us; speedup 1.0000x reference)
//
#include <hip/hip_runtime.h>
#include <math.h>

typedef __bf16 bf16;
typedef unsigned short u16;
typedef __bf16 bf16x8 __attribute__((ext_vector_type(8)));
typedef float f32x4 __attribute__((ext_vector_type(4)));

#define T_SEQ 2048
#define NB    2
#define CE    512
#define HD    64
#define ROWS  4096
#define LDT   40   // GEMM LDS stride (32+8)
#define LDA   72   // attn LDS stride (64+8)

#define MFMA16(a,b,c) __builtin_amdgcn_mfma_f32_16x16x32_bf16((a),(b),(c),0,0,0)

// weight-split element offsets (per-matrix, layer-0 base; layer stride noted)
#define O_SQ  0LL         // sWqkv  stride 786432
#define O_SWO 3145728LL   // sWo    stride 262144
#define O_CQ  4194304LL   // cWqkv  stride 786432
#define O_CWO 7340032LL   // cWo    stride 262144
#define O_F1  8388608LL   // fc1w   stride 1048576
#define O_F2  12582912LL  // fc2w   stride 1048576
#define O_E   16777216LL  // enc    (2*2048*512)

// bijective XCD-chunked swizzle (m204)
static __device__ __forceinline__ int xcd_swz(int id, int n) {
  int q = n >> 3, r = n & 7;
  int x = id & 7, o = id >> 3;
  return (x < r) ? (x * (q + 1) + o) : (r * (q + 1) + (x - r) * q + o);
}

static __device__ __forceinline__ float ldf(const void* src, size_t eoff, bool f32) {
  return f32 ? ((const float*)src)[eoff] : (float)((const bf16*)src)[eoff];
}

// =====================================================================
// Sniffer: flags[0]=fp32 storage; flags[1]=tokens int64; flags[2]=1 (act lo);
// flags[3]=enc lo nonzero (set by wprep); flags[4]=weight lo nonzero (wprep)
// =====================================================================
__global__ __launch_bounds__(256) void sniff(const u16* __restrict__ xs,
                                             const int* __restrict__ toks,
                                             int* __restrict__ flags)
{
  const int tid = threadIdx.x;
  int crazy = 0, ze = 0;
  for (int i = tid; i < 4096; i += 256) {
    int e = (xs[i] >> 7) & 0xFF;
    if (e >= 141) crazy++;
    if (((i & 1) == 0) && (xs[i] == 0)) ze++;
  }
  int zc = 0;
  for (int i = tid; i < 1024; i += 256)
    if (toks[2 * i + 1] == 0) zc++;
  __shared__ int r1[4], r2[4], r3[4];
#pragma unroll
  for (int o = 32; o; o >>= 1) {
    crazy += __shfl_down(crazy, o); ze += __shfl_down(ze, o); zc += __shfl_down(zc, o);
  }
  if ((tid & 63) == 0) { r1[tid >> 6] = crazy; r2[tid >> 6] = ze; r3[tid >> 6] = zc; }
  __syncthreads();
  if (tid == 0) {
    int c = r1[0] + r1[1] + r1[2] + r1[3];
    int z = r2[0] + r2[1] + r2[2] + r2[3];
    int t = r3[0] + r3[1] + r3[2] + r3[3];
    flags[0] = (z > 1500 || c > 64) ? 1 : 0;
    flags[1] = (t > 900) ? 1 : 0;
    flags[2] = 1;          // activation lo always present
    flags[3] = 0;          // enc lo (wprep ORs)
    flags[4] = 0;          // weight lo (wprep ORs)
  }
}

// =====================================================================
// One-time weight+enc split: raw (fp32 or bf16 storage) -> wh/wl bf16.
// grid (1024, 7); per-matrix nonzero-lo vote -> flags[3]/flags[4].
// =====================================================================
__global__ __launch_bounds__(256) void wprep(const void* w0, const void* w1, const void* w2,
                                             const void* w3, const void* w4, const void* w5,
                                             const void* w6,
                                             bf16* __restrict__ wh, bf16* __restrict__ wl,
                                             int* __restrict__ flags)
{
  const int m = blockIdx.y;
  const void* srcs[7] = {w0, w1, w2, w3, w4, w5, w6};
  const int sizes[7]  = {3145728, 1048576, 3145728, 1048576, 4194304, 4194304, 2097152};
  const long long offs[7] = {O_SQ, O_SWO, O_CQ, O_CWO, O_F1, O_F2, O_E};
  const void* src = srcs[m];
  const int sz = sizes[m];
  const long long off = offs[m];
  const bool fl = flags[0] != 0;
  long long i0 = ((long long)blockIdx.x * 256 + threadIdx.x) * 16;
  bool nz = false;
  if (i0 < sz) {
    float v[16];
    if (fl) {
      const float4* p = (const float4*)((const float*)src + i0);
#pragma unroll
      for (int q = 0; q < 4; q++) { float4 t = p[q]; v[4*q] = t.x; v[4*q+1] = t.y; v[4*q+2] = t.z; v[4*q+3] = t.w; }
    } else {
      const uint4* p = (const uint4*)((const bf16*)src + i0);
      uint4 a = p[0], b = p[1];
      const bf16* c0 = (const bf16*)&a; const bf16* c1 = (const bf16*)&b;
#pragma unroll
      for (int q = 0; q < 8; q++) { v[q] = (float)c0[q]; v[8+q] = (float)c1[q]; }
    }
    bf16x8 h0, h1, l0, l1;
#pragma unroll
    for (int q = 0; q < 8; q++) {
      bf16 a = (bf16)v[q], b = (bf16)v[8+q];
      h0[q] = a; h1[q] = b;
      float la = v[q] - (float)a, lb = v[8+q] - (float)b;
      l0[q] = (bf16)la; l1[q] = (bf16)lb;
      nz = nz || (la != 0.0f) || (lb != 0.0f);
    }
    *(bf16x8*)&wh[off + i0]     = h0;
    *(bf16x8*)&wh[off + i0 + 8] = h1;
    *(bf16x8*)&wl[off + i0]     = l0;
    *(bf16x8*)&wl[off + i0 + 8] = l1;
  }
  unsigned long long mv = __ballot(nz);
  if ((threadIdx.x & 63) == 0 && mv)
    atomicOr(&flags[(m == 6) ? 3 : 4], 1);
}

// =====================================================================
// Positional embedding: xf fp32 + xh/xl split
// =====================================================================
__global__ __launch_bounds__(256) void posembed(const void* __restrict__ xsrc,
                                                const int* __restrict__ toks,
                                                const int* __restrict__ flags,
                                                float* __restrict__ xf,
                                                bf16* __restrict__ xh, bf16* __restrict__ xl)
{
  const bool f32 = flags[0] != 0;
  const bool tok64 = flags[1] != 0;
  const int row = blockIdx.x;
  const int t = row >> 1, b = row & 1;
  const int tix = b * T_SEQ + t;
  const int tok = tok64 ? toks[2 * tix] : toks[tix];
  const int p = (tok != 0) ? (t + 1) : 0;
  const float kf = -0.0361193740f;
  for (int c = threadIdx.x; c < CE; c += 256) {
    float pe = 0.0f;
    if (p != 0) {
      int i = (c < 256) ? c : (c - 256);
      float freq = expf((float)i * kf);
      float ang = (float)p * freq;
      pe = (c < 256) ? sinf(ang) : cosf(ang);
    }
    float v = ldf(xsrc, (size_t)row * CE + c, f32) + pe;
    size_t o = (size_t)row * CE + c;
    xf[o] = v;
    bf16 hi = (bf16)v;
    xh[o] = hi; xl[o] = (bf16)(v - (float)hi);
  }
}

// =====================================================================
// Pure-bf16 MFMA GEMM: operands pre-split (hi/lo bf16). 1D grid + XCD
// swizzle, dbuf LDS, split-K, reg prefetch. Streams: hi*hi always,
// lo_a*hi if flags[aIdx], hi*lo_b if flags[bIdx].
// OUTM 0: fp32 (+bias at z0 if BIAS); OUTM 1: relu+bias -> bf16 split.
// =====================================================================
template<int OUTM, bool BIAS>
__global__ __launch_bounds__(256) void gemm_bb(const bf16* __restrict__ A1h, const bf16* __restrict__ A1l,
                                               const bf16* __restrict__ A2h, const bf16* __restrict__ A2l,
                                               const bf16* __restrict__ Bhg, const bf16* __restrict__ Blg,
                                               long long bOff,
                                               const void* __restrict__ bias, size_t biasOff,
                                               const int* __restrict__ flags,
                                               int aIdx1, int aIdx2, int bIdx,
                                               float* __restrict__ Cf,
                                               bf16* __restrict__ Coh, bf16* __restrict__ Col,
                                               int N, int K, int kspan, int nbx, int nbxA,
                                               long long partStride)
{
  __shared__ __align__(16) bf16 AhS[2][128 * LDT];
  __shared__ __align__(16) bf16 AlS[2][128 * LDT];
  __shared__ __align__(16) bf16 BhS[2][128 * LDT];
  __shared__ __align__(16) bf16 BlS[2][128 * LDT];
  const int id = xcd_swz((int)blockIdx.x, (int)gridDim.x);
  const int per_z = nbx * 32;
  const int zz = id / per_z;
  const int rem = id - zz * per_z;
  const int by = rem / nbx, bx = rem - by * nbx;
  const bf16* Ahg = (bx < nbxA) ? A1h : A2h;
  const bf16* Alg = (bx < nbxA) ? A1l : A2l;
  const bool alo = flags[(bx < nbxA) ? aIdx1 : aIdx2] != 0;
  const bool blo = flags[bIdx] != 0;
  const bool bfl = flags[0] != 0;
  const int tid = threadIdx.x;
  const int m0 = by * 128, n0 = bx * 128;
  const int srow = tid >> 1, skc = (tid & 1) * 16;
  const int wid = tid >> 6, lane = tid & 63;
  const int wm = (wid >> 1) * 64, wn = (wid & 1) * 64;
  const int fr = lane & 15, fk = (lane >> 4) * 8;
  const int kb = zz * kspan;
  const int ke = (kb + kspan < K) ? (kb + kspan) : K;
  f32x4 acc[4][4] = {};

  uint4 rah[2], ral[2], rbh[2], rbl[2];
  auto loadAB = [&](int k0) {
    size_t ga = (size_t)(m0 + srow) * K + k0 + skc;
    const uint4* pa = (const uint4*)(Ahg + ga);
    rah[0] = pa[0]; rah[1] = pa[1];
    if (alo) { const uint4* q = (const uint4*)(Alg + ga); ral[0] = q[0]; ral[1] = q[1]; }
    size_t gb = (size_t)bOff + (size_t)(n0 + srow) * K + k0 + skc;
    const uint4* pb = (const uint4*)(Bhg + gb);
    rbh[0] = pb[0]; rbh[1] = pb[1];
    if (blo) { const uint4* q = (const uint4*)(Blg + gb); rbl[0] = q[0]; rbl[1] = q[1]; }
  };
  auto storeAB = [&](int buf) {
    *(uint4*)&AhS[buf][srow * LDT + skc]     = rah[0];
    *(uint4*)&AhS[buf][srow * LDT + skc + 8] = rah[1];
    if (alo) {
      *(uint4*)&AlS[buf][srow * LDT + skc]     = ral[0];
      *(uint4*)&AlS[buf][srow * LDT + skc + 8] = ral[1];
    }
    *(uint4*)&BhS[buf][srow * LDT + skc]     = rbh[0];
    *(uint4*)&BhS[buf][srow * LDT + skc + 8] = rbh[1];
    if (blo) {
      *(uint4*)&BlS[buf][srow * LDT + skc]     = rbl[0];
      *(uint4*)&BlS[buf][srow * LDT + skc + 8] = rbl[1];
    }
  };

  loadAB(kb);
  storeAB(0);
  if (kb + 32 < ke) loadAB(kb + 32);

  int cur = 0;
  for (int k0 = kb; k0 < ke; k0 += 32) {
    __syncthreads();
    if (k0 + 32 < ke) {
      storeAB(cur ^ 1);
      if (k0 + 64 < ke) loadAB(k0 + 64);
    }
    const bf16* Ahc = AhS[cur]; const bf16* Alc = AlS[cur];
    const bf16* Bhc = BhS[cur]; const bf16* Blc = BlS[cur];
    bf16x8 ah[4], bh[4];
#pragma unroll
    for (int i = 0; i < 4; i++) ah[i] = *(const bf16x8*)&Ahc[(wm + i*16 + fr) * LDT + fk];
#pragma unroll
    for (int j = 0; j < 4; j++) bh[j] = *(const bf16x8*)&Bhc[(wn + j*16 + fr) * LDT + fk];
#pragma unroll
    for (int i = 0; i < 4; i++)
#pragma unroll
      for (int j = 0; j < 4; j++)
        acc[i][j] = MFMA16(ah[i], bh[j], acc[i][j]);
    if (alo) {
      bf16x8 al[4];
#pragma unroll
      for (int i = 0; i < 4; i++) al[i] = *(const bf16x8*)&Alc[(wm + i*16 + fr) * LDT + fk];
#pragma unroll
      for (int i = 0; i < 4; i++)
#pragma unroll
        for (int j = 0; j < 4; j++)
          acc[i][j] = MFMA16(al[i], bh[j], acc[i][j]);
    }
    if (blo) {
      bf16x8 bl[4];
#pragma unroll
      for (int j = 0; j < 4; j++) bl[j] = *(const bf16x8*)&Blc[(wn + j*16 + fr) * LDT + fk];
#pragma unroll
      for (int i = 0; i < 4; i++)
#pragma unroll
        for (int j = 0; j < 4; j++)
          acc[i][j] = MFMA16(ah[i], bl[j], acc[i][j]);
    }
    cur ^= 1;
  }
  const int orow0 = m0 + wm + (lane >> 4) * 4;
  const int ocol0 = n0 + wn + (lane & 15);
  if (OUTM == 0) {
    float* Cp = Cf + (long long)zz * partStride;
    const bool addb = BIAS && (zz == 0);
#pragma unroll
    for (int j = 0; j < 4; j++) {
      int col = ocol0 + j * 16;
      float bv = addb ? ldf(bias, biasOff + col, bfl) : 0.0f;
#pragma unroll
      for (int i = 0; i < 4; i++)
#pragma unroll
        for (int r = 0; r < 4; r++)
          Cp[(size_t)(orow0 + i * 16 + r) * N + col] = acc[i][j][r] + bv;
    }
  } else {
#pragma unroll
    for (int j = 0; j < 4; j++) {
      int col = ocol0 + j * 16;
      float bv = ldf(bias, biasOff + col, bfl);
#pragma unroll
      for (int i = 0; i < 4; i++)
#pragma unroll
        for (int r = 0; r < 4; r++) {
          float vv = fmaxf(acc[i][j][r] + bv, 0.0f);
          bf16 hi = (bf16)vv;
          size_t o = (size_t)(orow0 + i * 16 + r) * N + col;
          Coh[o] = hi; Col[o] = (bf16)(vv - (float)hi);
        }
    }
  }
}

// =====================================================================
// Fused K/V prepass (reads fp32 projections): K split -> kh/kl [bh][s][64];
// V transpose+split -> vth/vtl [bh][d][s]; per-chunk col sums vcs.
// =====================================================================
__global__ __launch_bounds__(256) void prep_kv(const float* __restrict__ base, int ld,
                                               int kofs0, int vofs0,
                                               bf16* __restrict__ kh, bf16* __restrict__ kl,
                                               bf16* __restrict__ vth, bf16* __restrict__ vtl,
                                               float* __restrict__ vcs)
{
  __shared__ float ts[64 * 65];
  const int bh = blockIdx.x, s0 = blockIdx.y * 64;
  const int b = bh >> 3, hq = bh & 7;
  const int kofs = kofs0 + hq * HD, vofs = vofs0 + hq * HD;
  const int tid = threadIdx.x;
#pragma unroll
  for (int it = 0; it < 16; ++it) {
    int idx = it * 256 + tid, r = idx >> 6, d = idx & 63;
    size_t rowb = (size_t)((s0 + r) * NB + b) * ld;
    float v = base[rowb + kofs + d];
    bf16 hi = (bf16)v;
    size_t o = ((size_t)bh * T_SEQ + s0 + r) * 64 + d;
    kh[o] = hi; kl[o] = (bf16)(v - (float)hi);
    ts[r * 65 + d] = base[rowb + vofs + d];
  }
  __syncthreads();
  const int d = tid >> 2, sseg = (tid & 3) * 16;
  bf16x8 hv0, lv0, hv1, lv1;
#pragma unroll
  for (int q = 0; q < 8; ++q) {
    float v0 = ts[(sseg + q) * 65 + d];
    float v1 = ts[(sseg + 8 + q) * 65 + d];
    bf16 h0 = (bf16)v0, h1 = (bf16)v1;
    hv0[q] = h0; lv0[q] = (bf16)(v0 - (float)h0);
    hv1[q] = h1; lv1[q] = (bf16)(v1 - (float)h1);
  }
  size_t o = ((size_t)bh * 64 + d) * T_SEQ + s0 + sseg;
  *(bf16x8*)&vth[o]     = hv0;
  *(bf16x8*)&vth[o + 8] = hv1;
  *(bf16x8*)&vtl[o]     = lv0;
  *(bf16x8*)&vtl[o + 8] = lv1;
  if (tid < 64) {
    float s = 0.0f;
    for (int j = 0; j < 64; ++j) s += ts[j * 65 + tid];
    vcs[((size_t)bh * 32 + blockIdx.y) * 64 + tid] = s;
  }
}

__device__ __forceinline__ int remap_ty(int ty) { return (ty < 16) ? ty : 47 - ty; }

// =====================================================================
// Fused attention: raw masked scores (3-term QK), min/max partials,
// raw PV (3-term) -> pv bf16 hi/lo split. Affine deferred past Wo.
// =====================================================================
template<bool MASK>
__global__ __launch_bounds__(256) void fattn(const float* __restrict__ qbase, int qld, int qofs0,
                                             const bf16* __restrict__ kh, const bf16* __restrict__ kl,
                                             const bf16* __restrict__ vth, const bf16* __restrict__ vtl,
                                             float* __restrict__ partial,
                                             bf16* __restrict__ pvh, bf16* __restrict__ pvl)
{
  __shared__ __align__(16) bf16 Qh[64 * LDA], Ql[64 * LDA];
  __shared__ __align__(16) bf16 Kh[64 * LDA], Kl[64 * LDA];
  __shared__ __align__(16) bf16 Vh[64 * LDA], Vl[64 * LDA];
  __shared__ __align__(16) bf16 Ph[64 * LDA], Pl[64 * LDA];
  __shared__ float rn[4], rx[4];
  const int id = xcd_swz((int)blockIdx.x, 512);
  const int bh = id >> 5;
  const int tyr = remap_ty(id & 31);
  const int t0 = tyr * 64;
  const int b = bh >> 3, hq = bh & 7;
  const int qofs = qofs0 + hq * HD;
  const int tid = threadIdx.x;
#pragma unroll
  for (int it = 0; it < 16; ++it) {
    int idx = it * 256 + tid, r = idx >> 6, d = idx & 63;
    float v = qbase[(size_t)((t0 + r) * NB + b) * qld + qofs + d] * 0.125f;
    bf16 hi = (bf16)v;
    Qh[r * LDA + d] = hi; Ql[r * LDA + d] = (bf16)(v - (float)hi);
  }
  const int wid = tid >> 6, lane = tid & 63;
  const int wm_ = (wid >> 1) * 32, wn_ = (wid & 1) * 32;
  const int fr = lane & 15, fko = (lane >> 4) * 8;
  const int crr = (lane >> 4) * 4, crc = lane & 15;
  const int cr = tid >> 2, cseg = (tid & 3) * 16;
  float mn = 1e30f, mx = -1e30f;
  f32x4 o4[2][2] = {};
  const int nch = MASK ? (tyr + 1) : 32;
  for (int sc = 0; sc < nch; ++sc) {
    const int s0 = sc * 64;
    __syncthreads();
    {
      size_t go = ((size_t)bh * T_SEQ + s0 + cr) * 64 + cseg;
      *(bf16x8*)&Kh[cr * LDA + cseg]     = *(const bf16x8*)&kh[go];
      *(bf16x8*)&Kh[cr * LDA + cseg + 8] = *(const bf16x8*)&kh[go + 8];
      *(bf16x8*)&Kl[cr * LDA + cseg]     = *(const bf16x8*)&kl[go];
      *(bf16x8*)&Kl[cr * LDA + cseg + 8] = *(const bf16x8*)&kl[go + 8];
      size_t gv = ((size_t)bh * 64 + cr) * T_SEQ + s0 + cseg;
      *(bf16x8*)&Vh[cr * LDA + cseg]     = *(const bf16x8*)&vth[gv];
      *(bf16x8*)&Vh[cr * LDA + cseg + 8] = *(const bf16x8*)&vth[gv + 8];
      *(bf16x8*)&Vl[cr * LDA + cseg]     = *(const bf16x8*)&vtl[gv];
      *(bf16x8*)&Vl[cr * LDA + cseg + 8] = *(const bf16x8*)&vtl[gv + 8];
    }
    __syncthreads();
    f32x4 a4[2][2] = {};
#pragma unroll
    for (int ks = 0; ks < 2; ++ks) {
      bf16x8 aH[2], aL[2], bH[2], bL[2];
#pragma unroll
      for (int i = 0; i < 2; ++i) {
        aH[i] = *(const bf16x8*)&Qh[(wm_ + i*16 + fr) * LDA + ks*32 + fko];
        aL[i] = *(const bf16x8*)&Ql[(wm_ + i*16 + fr) * LDA + ks*32 + fko];
        bH[i] = *(const bf16x8*)&Kh[(wn_ + i*16 + fr) * LDA + ks*32 + fko];
        bL[i] = *(const bf16x8*)&Kl[(wn_ + i*16 + fr) * LDA + ks*32 + fko];
      }
#pragma unroll
      for (int i = 0; i < 2; ++i)
#pragma unroll
        for (int j = 0; j < 2; ++j) {
          a4[i][j] = MFMA16(aH[i], bH[j], a4[i][j]);
          a4[i][j] = MFMA16(aL[i], bH[j], a4[i][j]);
          a4[i][j] = MFMA16(aH[i], bL[j], a4[i][j]);
        }
    }
#pragma unroll
    for (int i = 0; i < 2; ++i)
#pragma unroll
      for (int j = 0; j < 2; ++j)
#pragma unroll
        for (int r = 0; r < 4; ++r) {
          int tl = wm_ + i*16 + crr + r;
          int sl = wn_ + j*16 + crc;
          float w = a4[i][j][r];
          if (MASK && (s0 + sl) > (t0 + tl)) w = 0.0f;
          mn = fminf(mn, w); mx = fmaxf(mx, w);
          bf16 wh = (bf16)w;
          Ph[tl * LDA + sl] = wh;
          Pl[tl * LDA + sl] = (bf16)(w - (float)wh);
        }
    __syncthreads();
#pragma unroll
    for (int ks = 0; ks < 2; ++ks) {
      bf16x8 pH[2], pL[2], vH[2], vL[2];
#pragma unroll
      for (int i = 0; i < 2; ++i) {
        pH[i] = *(const bf16x8*)&Ph[(wm_ + i*16 + fr) * LDA + ks*32 + fko];
        pL[i] = *(const bf16x8*)&Pl[(wm_ + i*16 + fr) * LDA + ks*32 + fko];
        vH[i] = *(const bf16x8*)&Vh[(wn_ + i*16 + fr) * LDA + ks*32 + fko];
        vL[i] = *(const bf16x8*)&Vl[(wn_ + i*16 + fr) * LDA + ks*32 + fko];
      }
#pragma unroll
      for (int i = 0; i < 2; ++i)
#pragma unroll
        for (int j = 0; j < 2; ++j) {
          o4[i][j] = MFMA16(pH[i], vH[j], o4[i][j]);
          o4[i][j] = MFMA16(pL[i], vH[j], o4[i][j]);
          o4[i][j] = MFMA16(pH[i], vL[j], o4[i][j]);
        }
    }
  }
#pragma unroll
  for (int i = 0; i < 2; ++i)
#pragma unroll
    for (int j = 0; j < 2; ++j)
#pragma unroll
      for (int r = 0; r < 4; ++r) {
        int tl = wm_ + i*16 + crr + r;
        int dl = wn_ + j*16 + crc;
        float val = o4[i][j][r];
        bf16 hi = (bf16)val;
        size_t o = (size_t)((t0 + tl) * NB + b) * CE + hq * HD + dl;
        pvh[o] = hi; pvl[o] = (bf16)(val - (float)hi);
      }
#pragma unroll
  for (int o = 32; o; o >>= 1) { mn = fminf(mn, __shfl_down(mn, o)); mx = fmaxf(mx, __shfl_down(mx, o)); }
  if (lane == 0) { rn[wid] = mn; rx[wid] = mx; }
  __syncthreads();
  if (tid == 0) {
    partial[2 * id]     = fminf(fminf(rn[0], rn[1]), fminf(rn[2], rn[3]));
    partial[2 * id + 1] = fmaxf(fmaxf(rx[0], rx[1]), fmaxf(rx[2], rx[3]));
  }
}

// =====================================================================
// reduce 512 partial pairs -> mmf; total V colsum vsum[2*512]
// =====================================================================
__global__ __launch_bounds__(512) void reduce_mm(const float* __restrict__ partial,
                                                 const float* __restrict__ vcs,
                                                 float* __restrict__ mmf,
                                                 float* __restrict__ vsum)
{
  const int tid = threadIdx.x, w = tid >> 6, l = tid & 63;
  __shared__ float rn[8], rx[8];
  float mn = partial[2 * tid], mx = partial[2 * tid + 1];
#pragma unroll
  for (int o = 32; o; o >>= 1) { mn = fminf(mn, __shfl_down(mn, o)); mx = fmaxf(mx, __shfl_down(mx, o)); }
  if (l == 0) { rn[w] = mn; rx[w] = mx; }
  __syncthreads();
  if (tid == 0) {
    float a = 1e30f, c = -1e30f;
#pragma unroll
    for (int i = 0; i < 8; i++) { a = fminf(a, rn[i]); c = fmaxf(c, rx[i]); }
    mmf[0] = a; mmf[1] = c;
  }
  for (int e = tid; e < 1024; e += 512) {
    int bh = e >> 6, d = e & 63;
    float s = 0.0f;
#pragma unroll
    for (int ch = 0; ch < 32; ++ch) s += vcs[(size_t)bh * 2048 + ch * 64 + d];
    vsum[e] = s;
  }
}

// =====================================================================
// term[b*512+c] = -(mn*inv) * (vsum[b] @ Wo[c]) + bo[c]; grid 4x256
// =====================================================================
__global__ __launch_bounds__(256) void wo_term(const float* __restrict__ mmf,
                                               const float* __restrict__ vsum,
                                               const void* __restrict__ Wo, size_t woOff,
                                               const void* __restrict__ bo, size_t boOff,
                                               const int* __restrict__ flags,
                                               float* __restrict__ term)
{
  const bool fl = flags[0] != 0;
  const float inv = 1.0f / (mmf[1] - mmf[0]);
  const float cmn = mmf[0] * inv;
  int idx = blockIdx.x * 256 + threadIdx.x;      // 0..1023
  int b = idx >> 9, c = idx & 511;
  float s = 0.0f;
  for (int k = 0; k < 512; k++)
    s += vsum[b * 512 + k] * ldf(Wo, woOff + (size_t)c * 512 + k, fl);
  term[idx] = -cmn * s + ldf(bo, boOff + c, fl);
}

// =====================================================================
// LayerNorm(res + [AFF? inv*sum(NP partials)+term : sum(NP partials)])
// SPLIT: also emit bf16 hi/lo
// =====================================================================
template<int NP, bool AFF, bool SPLIT>
__global__ __launch_bounds__(256) void ln_sum(const float* __restrict__ res,
                                              const float* __restrict__ p, long long pstride,
                                              const void* __restrict__ g, const void* __restrict__ be,
                                              size_t goff, const int* __restrict__ flags,
                                              const float* __restrict__ mmf,
                                              const float* __restrict__ term,
                                              float* __restrict__ xfo,
                                              bf16* __restrict__ xh, bf16* __restrict__ xl)
{
  __shared__ float red[4];
  const bool fl = flags[0] != 0;
  const int tid = threadIdx.x;
  const size_t base = (size_t)blockIdx.x * CE;
  float pa = 0.0f, pb = 0.0f;
#pragma unroll
  for (int k = 0; k < NP; k++) {
    pa += p[(long long)k * pstride + base + tid];
    pb += p[(long long)k * pstride + base + tid + 256];
  }
  float a, b2;
  if (AFF) {
    const float inv = 1.0f / (mmf[1] - mmf[0]);
    const int b = blockIdx.x & 1;
    a  = res[base + tid]       + inv * pa + term[b * 512 + tid];
    b2 = res[base + tid + 256] + inv * pb + term[b * 512 + tid + 256];
  } else {
    a  = res[base + tid]       + pa;
    b2 = res[base + tid + 256] + pb;
  }
  float s = a + b2;
#pragma unroll
  for (int o = 32; o; o >>= 1) s += __shfl_down(s, o);
  if ((tid & 63) == 0) red[tid >> 6] = s;
  __syncthreads();
  float mu = (red[0] + red[1] + red[2] + red[3]) * (1.0f / 512.0f);
  __syncthreads();
  float da = a - mu, db = b2 - mu;
  float q = da * da + db * db;
#pragma unroll
  for (int o = 32; o; o >>= 1) q += __shfl_down(q, o);
  if ((tid & 63) == 0) red[tid >> 6] = q;
  __syncthreads();
  float var = (red[0] + red[1] + red[2] + red[3]) * (1.0f / 512.0f);
  float rs = rsqrtf(var + 1e-20f);
  float o1 = da * rs * ldf(g, goff + tid, fl)       + ldf(be, goff + tid, fl);
  float o2 = db * rs * ldf(g, goff + tid + 256, fl) + ldf(be, goff + tid + 256, fl);
  xfo[base + tid]       = o1;
  xfo[base + tid + 256] = o2;
  if (SPLIT) {
    bf16 h1 = (bf16)o1, h2 = (bf16)o2;
    xh[base + tid]       = h1; xl[base + tid]       = (bf16)(o1 - (float)h1);
    xh[base + tid + 256] = h2; xl[base + tid + 256] = (bf16)(o2 - (float)h2);
  }
}

// =====================================================================
extern "C" void kernel_launch(void* const* d_in, const int* in_sizes, int n_in,
                              void* d_out, int out_size, void* d_ws, size_t ws_size,
                              hipStream_t stream)
{
  (void)in_sizes; (void)n_in; (void)out_size; (void)ws_size;
  const void* x_in   = d_in[0];
  const void* enc_in = d_in[1];
  const int*  tokens = (const int*)d_in[2];
  const void* sWqkv = d_in[3];
  const void* sbqkv = d_in[4];
  const void* sWo   = d_in[5];
  const void* sbo   = d_in[6];
  const void* cWqkv = d_in[7];
  const void* cbqkv = d_in[8];
  const void* cWo   = d_in[9];
  const void* cbo   = d_in[10];
  const void* fc1w  = d_in[11];
  const void* fc1b  = d_in[12];
  const void* fc2w  = d_in[13];
  const void* fc2b  = d_in[14];
  const void* ln1g  = d_in[15];
  const void* ln1b  = d_in[16];
  const void* ln2g  = d_in[17];
  const void* ln2b  = d_in[18];
  const void* ln3g  = d_in[19];
  const void* ln3b  = d_in[20];

  char* ws = (char*)d_ws;
  size_t off = 0;
  auto alloc = [&](size_t bytes) -> char* {
    char* p = ws + off;
    off += (bytes + 255) & ~(size_t)255;
    return p;
  };
  // ~180 MiB total
  int*   flags   = (int*)  alloc(256);
  float* mmf     = (float*)alloc(256);
  float* vsum    = (float*)alloc(1024 * 4);
  float* partial = (float*)alloc(4096);
  float* term    = (float*)alloc(1024 * 4);
  float* xf      = (float*)alloc((size_t)ROWS * CE * 4);          //  8 MiB residual
  bf16*  xh      = (bf16*) alloc((size_t)ROWS * CE * 2);          //  4 MiB
  bf16*  xl      = (bf16*) alloc((size_t)ROWS * CE * 2);          //  4 MiB
  float* qkv     = (float*)alloc((size_t)ROWS * 2048 * 4);        // 32 MiB (proj fp32 / h split)
  bf16*  pvh     = (bf16*) alloc((size_t)ROWS * CE * 2);          //  4 MiB
  bf16*  pvl     = (bf16*) alloc((size_t)ROWS * CE * 2);          //  4 MiB
  float* pblk    = (float*)alloc((size_t)ROWS * CE * 4 * 4);      // 32 MiB split-K partials
  bf16*  khb     = (bf16*) alloc((size_t)16 * T_SEQ * 64 * 2);    //  4 MiB
  bf16*  klb     = (bf16*) alloc((size_t)16 * T_SEQ * 64 * 2);    //  4 MiB
  bf16*  vth     = (bf16*) alloc((size_t)16 * 64 * T_SEQ * 2);    //  4 MiB
  bf16*  vtl     = (bf16*) alloc((size_t)16 * 64 * T_SEQ * 2);    //  4 MiB
  float* vcs     = (float*)alloc((size_t)16 * 32 * 64 * 4);       // 128 KiB
  bf16*  wh      = (bf16*) alloc((size_t)18874368 * 2);           // 36 MiB weights+enc hi
  bf16*  wl      = (bf16*) alloc((size_t)18874368 * 2);           // 36 MiB weights+enc lo
  // h split aliases qkv (proj fp32 dead before fc1; h dead before next proj)
  bf16* hh = (bf16*)qkv;
  bf16* hl = (bf16*)qkv + (size_t)ROWS * 2048;
  const long long PS_FULL = (long long)ROWS * CE;

  sniff<<<1, 256, 0, stream>>>((const u16*)x_in, tokens, flags);
  posembed<<<ROWS, 256, 0, stream>>>(x_in, tokens, flags, xf, xh, xl);
  wprep<<<dim3(1024, 7), 256, 0, stream>>>(sWqkv, sWo, cWqkv, cWo, fc1w, fc2w, enc_in,
                                           wh, wl, flags);

  for (int l = 0; l < 4; l++) {
    // ---------------- self-attention ----------------
    gemm_bb<0, true><<<384, 256, 0, stream>>>(
        xh, xl, xh, xl, wh, wl, O_SQ + (long long)l * 786432,
        sbqkv, (size_t)l * 1536, flags, 2, 2, 4,
        qkv, nullptr, nullptr, 1536, 512, 512, 12, 12, 0);
    prep_kv<<<dim3(16, 32), 256, 0, stream>>>(qkv, 1536, 512, 1024, khb, klb, vth, vtl, vcs);
    fattn<true><<<512, 256, 0, stream>>>(qkv, 1536, 0, khb, klb, vth, vtl, partial, pvh, pvl);
    reduce_mm<<<1, 512, 0, stream>>>(partial, vcs, mmf, vsum);
    wo_term<<<4, 256, 0, stream>>>(mmf, vsum, sWo, (size_t)l * 262144, sbo, (size_t)l * 512,
                                   flags, term);
    gemm_bb<0, false><<<512, 256, 0, stream>>>(       // Wo raw-PV, split-K4
        pvh, pvl, pvh, pvl, wh, wl, O_SWO + (long long)l * 262144,
        sbo, 0, flags, 2, 2, 4,
        pblk, nullptr, nullptr, 512, 512, 128, 4, 4, PS_FULL);
    ln_sum<4, true, true><<<ROWS, 256, 0, stream>>>(
        xf, pblk, PS_FULL, ln1g, ln1b, (size_t)l * 512, flags, mmf, term, xf, xh, xl);

    // ---------------- cross-attention (merged q|kv, N=1536) ----------------
    gemm_bb<0, true><<<384, 256, 0, stream>>>(
        xh, xl, wh + O_E, wl + O_E, wh, wl, O_CQ + (long long)l * 786432,
        cbqkv, (size_t)l * 1536, flags, 2, 3, 4,
        qkv, nullptr, nullptr, 1536, 512, 512, 12, 4, 0);
    prep_kv<<<dim3(16, 32), 256, 0, stream>>>(qkv, 1536, 512, 1024, khb, klb, vth, vtl, vcs);
    fattn<false><<<512, 256, 0, stream>>>(qkv, 1536, 0, khb, klb, vth, vtl, partial, pvh, pvl);
    reduce_mm<<<1, 512, 0, stream>>>(partial, vcs, mmf, vsum);
    wo_term<<<4, 256, 0, stream>>>(mmf, vsum, cWo, (size_t)l * 262144, cbo, (size_t)l * 512,
                                   flags, term);
    gemm_bb<0, false><<<512, 256, 0, stream>>>(       // cWo raw-PV, split-K4
        pvh, pvl, pvh, pvl, wh, wl, O_CWO + (long long)l * 262144,
        cbo, 0, flags, 2, 2, 4,
        pblk, nullptr, nullptr, 512, 512, 128, 4, 4, PS_FULL);
    ln_sum<4, true, true><<<ROWS, 256, 0, stream>>>(
        xf, pblk, PS_FULL, ln2g, ln2b, (size_t)l * 512, flags, mmf, term, xf, xh, xl);

    // ---------------- FFN ----------------
    gemm_bb<1, true><<<512, 256, 0, stream>>>(        // fc1 -> relu -> h split
        xh, xl, xh, xl, wh, wl, O_F1 + (long long)l * 1048576,
        fc1b, (size_t)l * 2048, flags, 2, 2, 4,
        nullptr, hh, hl, 2048, 512, 512, 16, 16, 0);
    gemm_bb<0, true><<<512, 256, 0, stream>>>(        // fc2 split-K4
        hh, hl, hh, hl, wh, wl, O_F2 + (long long)l * 1048576,
        fc2b, (size_t)l * 512, flags, 2, 2, 4,
        pblk, nullptr, nullptr, 512, 2048, 512, 4, 4, PS_FULL);
    if (l == 3) {
      ln_sum<4, false, false><<<ROWS, 256, 0, stream>>>(
          xf, pblk, PS_FULL, ln3g, ln3b, (size_t)l * 512, flags, nullptr, nullptr,
          (float*)d_out, nullptr, nullptr);
    } else {
      ln_sum<4, false, true><<<ROWS, 256, 0, stream>>>(
          xf, pblk, PS_FULL, ln3g, ln3b, (size_t)l * 512, flags, nullptr, nullptr,
          xf, xh, xl);
    }
  }
}

// Round 7
// 2999.229 us; speedup vs baseline: 1.0716x; 1.0716x over previous
//
#include <hip/hip_runtime.h>
#include <math.h>

typedef __bf16 bf16;
typedef unsigned short u16;
typedef __bf16 bf16x8 __attribute__((ext_vector_type(8)));
typedef float f32x4 __attribute__((ext_vector_type(4)));

#define T_SEQ 2048
#define NB    2
#define CE    512
#define HD    64
#define ROWS  4096
#define LDT   40   // GEMM LDS stride (32+8)
#define LDA   72   // attn LDS stride (64+8)

#define MFMA16(a,b,c) __builtin_amdgcn_mfma_f32_16x16x32_bf16((a),(b),(c),0,0,0)

// weight-split element offsets (only used when inputs are fp32 storage)
#define O_SQ  0LL         // sWqkv  stride 786432
#define O_SWO 3145728LL   // sWo    stride 262144
#define O_CQ  4194304LL   // cWqkv  stride 786432
#define O_CWO 7340032LL   // cWo    stride 262144
#define O_F1  8388608LL   // fc1w   stride 1048576
#define O_F2  12582912LL  // fc2w   stride 1048576
#define O_E   16777216LL  // enc

// bijective XCD-chunked swizzle (m204)
static __device__ __forceinline__ int xcd_swz(int id, int n) {
  int q = n >> 3, r = n & 7;
  int x = id & 7, o = id >> 3;
  return (x < r) ? (x * (q + 1) + o) : (r * (q + 1) + (x - r) * q + o);
}

static __device__ __forceinline__ float ldf(const void* src, size_t eoff, bool f32) {
  return f32 ? ((const float*)src)[eoff] : (float)((const bf16*)src)[eoff];
}

// =====================================================================
// Sniffer: flags[0]=fp32 storage; flags[1]=tokens int64;
// flags[3]=enc lo nonzero (wprep); flags[4]=weight lo nonzero (wprep)
// =====================================================================
__global__ __launch_bounds__(256) void sniff(const u16* __restrict__ xs,
                                             const int* __restrict__ toks,
                                             int* __restrict__ flags)
{
  const int tid = threadIdx.x;
  int crazy = 0, ze = 0;
  for (int i = tid; i < 4096; i += 256) {
    int e = (xs[i] >> 7) & 0xFF;
    if (e >= 141) crazy++;
    if (((i & 1) == 0) && (xs[i] == 0)) ze++;
  }
  int zc = 0;
  for (int i = tid; i < 1024; i += 256)
    if (toks[2 * i + 1] == 0) zc++;
  __shared__ int r1[4], r2[4], r3[4];
#pragma unroll
  for (int o = 32; o; o >>= 1) {
    crazy += __shfl_down(crazy, o); ze += __shfl_down(ze, o); zc += __shfl_down(zc, o);
  }
  if ((tid & 63) == 0) { r1[tid >> 6] = crazy; r2[tid >> 6] = ze; r3[tid >> 6] = zc; }
  __syncthreads();
  if (tid == 0) {
    int c = r1[0] + r1[1] + r1[2] + r1[3];
    int z = r2[0] + r2[1] + r2[2] + r2[3];
    int t = r3[0] + r3[1] + r3[2] + r3[3];
    flags[0] = (z > 1500 || c > 64) ? 1 : 0;
    flags[1] = (t > 900) ? 1 : 0;
    flags[2] = 1;
    flags[3] = 0;
    flags[4] = 0;
  }
}

// =====================================================================
// Weight+enc split, ONLY when fp32 storage (early exit otherwise: with
// bf16 storage the raw tensors are used directly and lo == 0 provably).
// =====================================================================
__global__ __launch_bounds__(256) void wprep(const void* w0, const void* w1, const void* w2,
                                             const void* w3, const void* w4, const void* w5,
                                             const void* w6,
                                             bf16* __restrict__ wh, bf16* __restrict__ wl,
                                             int* __restrict__ flags)
{
  if (flags[0] == 0) return;          // bf16 storage: nothing to do
  const int m = blockIdx.y;
  const void* srcs[7] = {w0, w1, w2, w3, w4, w5, w6};
  const int sizes[7]  = {3145728, 1048576, 3145728, 1048576, 4194304, 4194304, 2097152};
  const long long offs[7] = {O_SQ, O_SWO, O_CQ, O_CWO, O_F1, O_F2, O_E};
  const void* src = srcs[m];
  const int sz = sizes[m];
  const long long off = offs[m];
  long long i0 = ((long long)blockIdx.x * 256 + threadIdx.x) * 16;
  bool nz = false;
  if (i0 < sz) {
    float v[16];
    const float4* p = (const float4*)((const float*)src + i0);
#pragma unroll
    for (int q = 0; q < 4; q++) { float4 t = p[q]; v[4*q] = t.x; v[4*q+1] = t.y; v[4*q+2] = t.z; v[4*q+3] = t.w; }
    bf16x8 h0, h1, l0, l1;
#pragma unroll
    for (int q = 0; q < 8; q++) {
      bf16 a = (bf16)v[q], b = (bf16)v[8+q];
      h0[q] = a; h1[q] = b;
      float la = v[q] - (float)a, lb = v[8+q] - (float)b;
      l0[q] = (bf16)la; l1[q] = (bf16)lb;
      nz = nz || (la != 0.0f) || (lb != 0.0f);
    }
    *(bf16x8*)&wh[off + i0]     = h0;
    *(bf16x8*)&wh[off + i0 + 8] = h1;
    *(bf16x8*)&wl[off + i0]     = l0;
    *(bf16x8*)&wl[off + i0 + 8] = l1;
  }
  unsigned long long mv = __ballot(nz);
  if ((threadIdx.x & 63) == 0 && mv)
    atomicOr(&flags[(m == 6) ? 3 : 4], 1);
}

// =====================================================================
// Positional embedding: xf fp32 + xh/xl split
// =====================================================================
__global__ __launch_bounds__(256) void posembed(const void* __restrict__ xsrc,
                                                const int* __restrict__ toks,
                                                const int* __restrict__ flags,
                                                float* __restrict__ xf,
                                                bf16* __restrict__ xh, bf16* __restrict__ xl)
{
  const bool f32 = flags[0] != 0;
  const bool tok64 = flags[1] != 0;
  const int row = blockIdx.x;
  const int t = row >> 1, b = row & 1;
  const int tix = b * T_SEQ + t;
  const int tok = tok64 ? toks[2 * tix] : toks[tix];
  const int p = (tok != 0) ? (t + 1) : 0;
  const float kf = -0.0361193740f;
  for (int c = threadIdx.x; c < CE; c += 256) {
    float pe = 0.0f;
    if (p != 0) {
      int i = (c < 256) ? c : (c - 256);
      float freq = expf((float)i * kf);
      float ang = (float)p * freq;
      pe = (c < 256) ? sinf(ang) : cosf(ang);
    }
    float v = ldf(xsrc, (size_t)row * CE + c, f32) + pe;
    size_t o = (size_t)row * CE + c;
    xf[o] = v;
    bf16 hi = (bf16)v;
    xh[o] = hi; xl[o] = (bf16)(v - (float)hi);
  }
}

// =====================================================================
// Pure-bf16 MFMA GEMM. A1 = split activations (always hi+lo). A2 (bx>=nbxA)
// = enc: raw bf16 when bf16 storage, split buffer when fp32 storage.
// B = weights: raw bf16 when bf16 storage (lo off), split when fp32.
// 1D grid + XCD swizzle, dbuf LDS (1 barrier/K-step), split-K, prefetch.
// OUTM 0: fp32 (+bias at z0 if BIAS); OUTM 1: relu+bias -> bf16 hi/lo.
// =====================================================================
template<int OUTM, bool BIAS>
__global__ __launch_bounds__(256) void gemm_bb(const bf16* __restrict__ A1h, const bf16* __restrict__ A1l,
                                               const void* __restrict__ A2raw,
                                               const bf16* __restrict__ wsp_h, const bf16* __restrict__ wsp_l,
                                               long long a2SplitOff,
                                               const void* __restrict__ Braw, long long bRawOff,
                                               long long bSplitOff,
                                               const void* __restrict__ bias, size_t biasOff,
                                               const int* __restrict__ flags,
                                               float* __restrict__ Cf,
                                               bf16* __restrict__ Coh, bf16* __restrict__ Col,
                                               int N, int K, int kspan, int nbx, int nbxA,
                                               long long partStride)
{
  __shared__ __align__(16) bf16 AhS[2][128 * LDT];
  __shared__ __align__(16) bf16 AlS[2][128 * LDT];
  __shared__ __align__(16) bf16 BhS[2][128 * LDT];
  __shared__ __align__(16) bf16 BlS[2][128 * LDT];
  const int id = xcd_swz((int)blockIdx.x, (int)gridDim.x);
  const int per_z = nbx * 32;
  const int zz = id / per_z;
  const int rem = id - zz * per_z;
  const int by = rem / nbx, bx = rem - by * nbx;
  const bool bfl = flags[0] != 0;
  // B operand
  const bf16* Bhg = bfl ? (wsp_h + bSplitOff) : ((const bf16*)Braw + bRawOff);
  const bf16* Blg = wsp_l + bSplitOff;
  const bool blo = bfl && (flags[4] != 0);
  // A operand
  const bf16* Ahg; const bf16* Alg; bool alo;
  if (bx < nbxA) { Ahg = A1h; Alg = A1l; alo = true; }
  else if (bfl)  { Ahg = wsp_h + a2SplitOff; Alg = wsp_l + a2SplitOff; alo = (flags[3] != 0); }
  else           { Ahg = (const bf16*)A2raw; Alg = A1l; alo = false; }
  const int tid = threadIdx.x;
  const int m0 = by * 128, n0 = bx * 128;
  const int srow = tid >> 1, skc = (tid & 1) * 16;
  const int wid = tid >> 6, lane = tid & 63;
  const int wm = (wid >> 1) * 64, wn = (wid & 1) * 64;
  const int fr = lane & 15, fk = (lane >> 4) * 8;
  const int kb = zz * kspan;
  const int ke = (kb + kspan < K) ? (kb + kspan) : K;
  f32x4 acc[4][4] = {};

  uint4 rah[2], ral[2], rbh[2], rbl[2];
  auto loadAB = [&](int k0) {
    size_t ga = (size_t)(m0 + srow) * K + k0 + skc;
    const uint4* pa = (const uint4*)(Ahg + ga);
    rah[0] = pa[0]; rah[1] = pa[1];
    if (alo) { const uint4* q = (const uint4*)(Alg + ga); ral[0] = q[0]; ral[1] = q[1]; }
    size_t gb = (size_t)(n0 + srow) * K + k0 + skc;
    const uint4* pb = (const uint4*)(Bhg + gb);
    rbh[0] = pb[0]; rbh[1] = pb[1];
    if (blo) { const uint4* q = (const uint4*)(Blg + gb); rbl[0] = q[0]; rbl[1] = q[1]; }
  };
  auto storeAB = [&](int buf) {
    *(uint4*)&AhS[buf][srow * LDT + skc]     = rah[0];
    *(uint4*)&AhS[buf][srow * LDT + skc + 8] = rah[1];
    if (alo) {
      *(uint4*)&AlS[buf][srow * LDT + skc]     = ral[0];
      *(uint4*)&AlS[buf][srow * LDT + skc + 8] = ral[1];
    }
    *(uint4*)&BhS[buf][srow * LDT + skc]     = rbh[0];
    *(uint4*)&BhS[buf][srow * LDT + skc + 8] = rbh[1];
    if (blo) {
      *(uint4*)&BlS[buf][srow * LDT + skc]     = rbl[0];
      *(uint4*)&BlS[buf][srow * LDT + skc + 8] = rbl[1];
    }
  };

  loadAB(kb);
  storeAB(0);
  if (kb + 32 < ke) loadAB(kb + 32);

  int cur = 0;
  for (int k0 = kb; k0 < ke; k0 += 32) {
    __syncthreads();
    if (k0 + 32 < ke) {
      storeAB(cur ^ 1);
      if (k0 + 64 < ke) loadAB(k0 + 64);
    }
    const bf16* Ahc = AhS[cur]; const bf16* Alc = AlS[cur];
    const bf16* Bhc = BhS[cur]; const bf16* Blc = BlS[cur];
    bf16x8 ah[4], bh[4];
#pragma unroll
    for (int i = 0; i < 4; i++) ah[i] = *(const bf16x8*)&Ahc[(wm + i*16 + fr) * LDT + fk];
#pragma unroll
    for (int j = 0; j < 4; j++) bh[j] = *(const bf16x8*)&Bhc[(wn + j*16 + fr) * LDT + fk];
#pragma unroll
    for (int i = 0; i < 4; i++)
#pragma unroll
      for (int j = 0; j < 4; j++)
        acc[i][j] = MFMA16(ah[i], bh[j], acc[i][j]);
    if (alo) {
      bf16x8 al[4];
#pragma unroll
      for (int i = 0; i < 4; i++) al[i] = *(const bf16x8*)&Alc[(wm + i*16 + fr) * LDT + fk];
#pragma unroll
      for (int i = 0; i < 4; i++)
#pragma unroll
        for (int j = 0; j < 4; j++)
          acc[i][j] = MFMA16(al[i], bh[j], acc[i][j]);
    }
    if (blo) {
      bf16x8 bl[4];
#pragma unroll
      for (int j = 0; j < 4; j++) bl[j] = *(const bf16x8*)&Blc[(wn + j*16 + fr) * LDT + fk];
#pragma unroll
      for (int i = 0; i < 4; i++)
#pragma unroll
        for (int j = 0; j < 4; j++)
          acc[i][j] = MFMA16(ah[i], bl[j], acc[i][j]);
    }
    cur ^= 1;
  }
  const int orow0 = m0 + wm + (lane >> 4) * 4;
  const int ocol0 = n0 + wn + (lane & 15);
  if (OUTM == 0) {
    float* Cp = Cf + (long long)zz * partStride;
    const bool addb = BIAS && (zz == 0);
#pragma unroll
    for (int j = 0; j < 4; j++) {
      int col = ocol0 + j * 16;
      float bv = addb ? ldf(bias, biasOff + col, bfl) : 0.0f;
#pragma unroll
      for (int i = 0; i < 4; i++)
#pragma unroll
        for (int r = 0; r < 4; r++)
          Cp[(size_t)(orow0 + i * 16 + r) * N + col] = acc[i][j][r] + bv;
    }
  } else {
#pragma unroll
    for (int j = 0; j < 4; j++) {
      int col = ocol0 + j * 16;
      float bv = ldf(bias, biasOff + col, bfl);
#pragma unroll
      for (int i = 0; i < 4; i++)
#pragma unroll
        for (int r = 0; r < 4; r++) {
          float vv = fmaxf(acc[i][j][r] + bv, 0.0f);
          bf16 hi = (bf16)vv;
          size_t o = (size_t)(orow0 + i * 16 + r) * N + col;
          Coh[o] = hi; Col[o] = (bf16)(vv - (float)hi);
        }
    }
  }
}

// =====================================================================
// Fused K/V prepass: K split -> kh/kl [bh][s][64]; V transpose+split ->
// vth/vtl [bh][d][s]; per-chunk col sums vcs.
// =====================================================================
__global__ __launch_bounds__(256) void prep_kv(const float* __restrict__ base, int ld,
                                               int kofs0, int vofs0,
                                               bf16* __restrict__ kh, bf16* __restrict__ kl,
                                               bf16* __restrict__ vth, bf16* __restrict__ vtl,
                                               float* __restrict__ vcs)
{
  __shared__ float ts[64 * 65];
  const int bh = blockIdx.x, s0 = blockIdx.y * 64;
  const int b = bh >> 3, hq = bh & 7;
  const int kofs = kofs0 + hq * HD, vofs = vofs0 + hq * HD;
  const int tid = threadIdx.x;
#pragma unroll
  for (int it = 0; it < 16; ++it) {
    int idx = it * 256 + tid, r = idx >> 6, d = idx & 63;
    size_t rowb = (size_t)((s0 + r) * NB + b) * ld;
    float v = base[rowb + kofs + d];
    bf16 hi = (bf16)v;
    size_t o = ((size_t)bh * T_SEQ + s0 + r) * 64 + d;
    kh[o] = hi; kl[o] = (bf16)(v - (float)hi);
    ts[r * 65 + d] = base[rowb + vofs + d];
  }
  __syncthreads();
  const int d = tid >> 2, sseg = (tid & 3) * 16;
  bf16x8 hv0, lv0, hv1, lv1;
#pragma unroll
  for (int q = 0; q < 8; ++q) {
    float v0 = ts[(sseg + q) * 65 + d];
    float v1 = ts[(sseg + 8 + q) * 65 + d];
    bf16 h0 = (bf16)v0, h1 = (bf16)v1;
    hv0[q] = h0; lv0[q] = (bf16)(v0 - (float)h0);
    hv1[q] = h1; lv1[q] = (bf16)(v1 - (float)h1);
  }
  size_t o = ((size_t)bh * 64 + d) * T_SEQ + s0 + sseg;
  *(bf16x8*)&vth[o]     = hv0;
  *(bf16x8*)&vth[o + 8] = hv1;
  *(bf16x8*)&vtl[o]     = lv0;
  *(bf16x8*)&vtl[o + 8] = lv1;
  if (tid < 64) {
    float s = 0.0f;
    for (int j = 0; j < 64; ++j) s += ts[j * 65 + tid];
    vcs[((size_t)bh * 32 + blockIdx.y) * 64 + tid] = s;
  }
}

__device__ __forceinline__ int remap_ty(int ty) { return (ty < 16) ? ty : 47 - ty; }

// =====================================================================
// Fused attention: raw masked scores (3-term QK), min/max partials,
// raw PV (3-term) -> pv bf16 hi/lo split. Affine deferred past Wo.
// =====================================================================
template<bool MASK>
__global__ __launch_bounds__(256) void fattn(const float* __restrict__ qbase, int qld, int qofs0,
                                             const bf16* __restrict__ kh, const bf16* __restrict__ kl,
                                             const bf16* __restrict__ vth, const bf16* __restrict__ vtl,
                                             float* __restrict__ partial,
                                             bf16* __restrict__ pvh, bf16* __restrict__ pvl)
{
  __shared__ __align__(16) bf16 Qh[64 * LDA], Ql[64 * LDA];
  __shared__ __align__(16) bf16 Kh[64 * LDA], Kl[64 * LDA];
  __shared__ __align__(16) bf16 Vh[64 * LDA], Vl[64 * LDA];
  __shared__ __align__(16) bf16 Ph[64 * LDA], Pl[64 * LDA];
  __shared__ float rn[4], rx[4];
  const int id = xcd_swz((int)blockIdx.x, 512);
  const int bh = id >> 5;
  const int tyr = remap_ty(id & 31);
  const int t0 = tyr * 64;
  const int b = bh >> 3, hq = bh & 7;
  const int qofs = qofs0 + hq * HD;
  const int tid = threadIdx.x;
#pragma unroll
  for (int it = 0; it < 16; ++it) {
    int idx = it * 256 + tid, r = idx >> 6, d = idx & 63;
    float v = qbase[(size_t)((t0 + r) * NB + b) * qld + qofs + d] * 0.125f;
    bf16 hi = (bf16)v;
    Qh[r * LDA + d] = hi; Ql[r * LDA + d] = (bf16)(v - (float)hi);
  }
  const int wid = tid >> 6, lane = tid & 63;
  const int wm_ = (wid >> 1) * 32, wn_ = (wid & 1) * 32;
  const int fr = lane & 15, fko = (lane >> 4) * 8;
  const int crr = (lane >> 4) * 4, crc = lane & 15;
  const int cr = tid >> 2, cseg = (tid & 3) * 16;
  float mn = 1e30f, mx = -1e30f;
  f32x4 o4[2][2] = {};
  const int nch = MASK ? (tyr + 1) : 32;
  for (int sc = 0; sc < nch; ++sc) {
    const int s0 = sc * 64;
    __syncthreads();
    {
      size_t go = ((size_t)bh * T_SEQ + s0 + cr) * 64 + cseg;
      *(bf16x8*)&Kh[cr * LDA + cseg]     = *(const bf16x8*)&kh[go];
      *(bf16x8*)&Kh[cr * LDA + cseg + 8] = *(const bf16x8*)&kh[go + 8];
      *(bf16x8*)&Kl[cr * LDA + cseg]     = *(const bf16x8*)&kl[go];
      *(bf16x8*)&Kl[cr * LDA + cseg + 8] = *(const bf16x8*)&kl[go + 8];
      size_t gv = ((size_t)bh * 64 + cr) * T_SEQ + s0 + cseg;
      *(bf16x8*)&Vh[cr * LDA + cseg]     = *(const bf16x8*)&vth[gv];
      *(bf16x8*)&Vh[cr * LDA + cseg + 8] = *(const bf16x8*)&vth[gv + 8];
      *(bf16x8*)&Vl[cr * LDA + cseg]     = *(const bf16x8*)&vtl[gv];
      *(bf16x8*)&Vl[cr * LDA + cseg + 8] = *(const bf16x8*)&vtl[gv + 8];
    }
    __syncthreads();
    f32x4 a4[2][2] = {};
#pragma unroll
    for (int ks = 0; ks < 2; ++ks) {
      bf16x8 aH[2], aL[2], bH[2], bL[2];
#pragma unroll
      for (int i = 0; i < 2; ++i) {
        aH[i] = *(const bf16x8*)&Qh[(wm_ + i*16 + fr) * LDA + ks*32 + fko];
        aL[i] = *(const bf16x8*)&Ql[(wm_ + i*16 + fr) * LDA + ks*32 + fko];
        bH[i] = *(const bf16x8*)&Kh[(wn_ + i*16 + fr) * LDA + ks*32 + fko];
        bL[i] = *(const bf16x8*)&Kl[(wn_ + i*16 + fr) * LDA + ks*32 + fko];
      }
#pragma unroll
      for (int i = 0; i < 2; ++i)
#pragma unroll
        for (int j = 0; j < 2; ++j) {
          a4[i][j] = MFMA16(aH[i], bH[j], a4[i][j]);
          a4[i][j] = MFMA16(aL[i], bH[j], a4[i][j]);
          a4[i][j] = MFMA16(aH[i], bL[j], a4[i][j]);
        }
    }
#pragma unroll
    for (int i = 0; i < 2; ++i)
#pragma unroll
      for (int j = 0; j < 2; ++j)
#pragma unroll
        for (int r = 0; r < 4; ++r) {
          int tl = wm_ + i*16 + crr + r;
          int sl = wn_ + j*16 + crc;
          float w = a4[i][j][r];
          if (MASK && (s0 + sl) > (t0 + tl)) w = 0.0f;
          mn = fminf(mn, w); mx = fmaxf(mx, w);
          bf16 wh = (bf16)w;
          Ph[tl * LDA + sl] = wh;
          Pl[tl * LDA + sl] = (bf16)(w - (float)wh);
        }
    __syncthreads();
#pragma unroll
    for (int ks = 0; ks < 2; ++ks) {
      bf16x8 pH[2], pL[2], vH[2], vL[2];
#pragma unroll
      for (int i = 0; i < 2; ++i) {
        pH[i] = *(const bf16x8*)&Ph[(wm_ + i*16 + fr) * LDA + ks*32 + fko];
        pL[i] = *(const bf16x8*)&Pl[(wm_ + i*16 + fr) * LDA + ks*32 + fko];
        vH[i] = *(const bf16x8*)&Vh[(wn_ + i*16 + fr) * LDA + ks*32 + fko];
        vL[i] = *(const bf16x8*)&Vl[(wn_ + i*16 + fr) * LDA + ks*32 + fko];
      }
#pragma unroll
      for (int i = 0; i < 2; ++i)
#pragma unroll
        for (int j = 0; j < 2; ++j) {
          o4[i][j] = MFMA16(pH[i], vH[j], o4[i][j]);
          o4[i][j] = MFMA16(pL[i], vH[j], o4[i][j]);
          o4[i][j] = MFMA16(pH[i], vL[j], o4[i][j]);
        }
    }
  }
#pragma unroll
  for (int i = 0; i < 2; ++i)
#pragma unroll
    for (int j = 0; j < 2; ++j)
#pragma unroll
      for (int r = 0; r < 4; ++r) {
        int tl = wm_ + i*16 + crr + r;
        int dl = wn_ + j*16 + crc;
        float val = o4[i][j][r];
        bf16 hi = (bf16)val;
        size_t o = (size_t)((t0 + tl) * NB + b) * CE + hq * HD + dl;
        pvh[o] = hi; pvl[o] = (bf16)(val - (float)hi);
      }
#pragma unroll
  for (int o = 32; o; o >>= 1) { mn = fminf(mn, __shfl_down(mn, o)); mx = fmaxf(mx, __shfl_down(mx, o)); }
  if (lane == 0) { rn[wid] = mn; rx[wid] = mx; }
  __syncthreads();
  if (tid == 0) {
    partial[2 * id]     = fminf(fminf(rn[0], rn[1]), fminf(rn[2], rn[3]));
    partial[2 * id + 1] = fmaxf(fmaxf(rx[0], rx[1]), fmaxf(rx[2], rx[3]));
  }
}

// =====================================================================
// reduce 512 partial pairs -> mmf; total V colsum vsum[2*512]
// =====================================================================
__global__ __launch_bounds__(512) void reduce_mm(const float* __restrict__ partial,
                                                 const float* __restrict__ vcs,
                                                 float* __restrict__ mmf,
                                                 float* __restrict__ vsum)
{
  const int tid = threadIdx.x, w = tid >> 6, l = tid & 63;
  __shared__ float rn[8], rx[8];
  float mn = partial[2 * tid], mx = partial[2 * tid + 1];
#pragma unroll
  for (int o = 32; o; o >>= 1) { mn = fminf(mn, __shfl_down(mn, o)); mx = fmaxf(mx, __shfl_down(mx, o)); }
  if (l == 0) { rn[w] = mn; rx[w] = mx; }
  __syncthreads();
  if (tid == 0) {
    float a = 1e30f, c = -1e30f;
#pragma unroll
    for (int i = 0; i < 8; i++) { a = fminf(a, rn[i]); c = fmaxf(c, rx[i]); }
    mmf[0] = a; mmf[1] = c;
  }
  for (int e = tid; e < 1024; e += 512) {
    int bh = e >> 6, d = e & 63;
    float s = 0.0f;
#pragma unroll
    for (int ch = 0; ch < 32; ++ch) s += vcs[(size_t)bh * 2048 + ch * 64 + d];
    vsum[e] = s;
  }
}

// =====================================================================
// term[b*512+c] = -(mn*inv)*(vsum[b]@Wo[c]) + bo[c]; 8 blocks, 2 thr/out
// =====================================================================
__global__ __launch_bounds__(256) void wo_term(const float* __restrict__ mmf,
                                               const float* __restrict__ vsum,
                                               const void* __restrict__ Wo, size_t woOff,
                                               const void* __restrict__ bo, size_t boOff,
                                               const int* __restrict__ flags,
                                               float* __restrict__ term)
{
  const bool fl = flags[0] != 0;
  const float inv = 1.0f / (mmf[1] - mmf[0]);
  const float cmn = mmf[0] * inv;
  int idx = blockIdx.x * 128 + (threadIdx.x >> 1);   // 0..1023
  int b = idx >> 9, c = idx & 511;
  int k0 = (threadIdx.x & 1) * 256;
  float s = 0.0f;
#pragma unroll 8
  for (int k = 0; k < 256; k++)
    s += vsum[b * 512 + k0 + k] * ldf(Wo, woOff + (size_t)c * 512 + k0 + k, fl);
  s += __shfl_down(s, 1);
  if ((threadIdx.x & 1) == 0)
    term[idx] = -cmn * s + ldf(bo, boOff + c, fl);
}

// =====================================================================
// LayerNorm(res + [AFF? inv*sum(NP partials)+term : sum(NP partials)])
// SPLIT: also emit bf16 hi/lo
// =====================================================================
template<int NP, bool AFF, bool SPLIT>
__global__ __launch_bounds__(256) void ln_sum(const float* __restrict__ res,
                                              const float* __restrict__ p, long long pstride,
                                              const void* __restrict__ g, const void* __restrict__ be,
                                              size_t goff, const int* __restrict__ flags,
                                              const float* __restrict__ mmf,
                                              const float* __restrict__ term,
                                              float* __restrict__ xfo,
                                              bf16* __restrict__ xh, bf16* __restrict__ xl)
{
  __shared__ float red[4];
  const bool fl = flags[0] != 0;
  const int tid = threadIdx.x;
  const size_t base = (size_t)blockIdx.x * CE;
  float pa = 0.0f, pb = 0.0f;
#pragma unroll
  for (int k = 0; k < NP; k++) {
    pa += p[(long long)k * pstride + base + tid];
    pb += p[(long long)k * pstride + base + tid + 256];
  }
  float a, b2;
  if (AFF) {
    const float inv = 1.0f / (mmf[1] - mmf[0]);
    const int b = blockIdx.x & 1;
    a  = res[base + tid]       + inv * pa + term[b * 512 + tid];
    b2 = res[base + tid + 256] + inv * pb + term[b * 512 + tid + 256];
  } else {
    a  = res[base + tid]       + pa;
    b2 = res[base + tid + 256] + pb;
  }
  float s = a + b2;
#pragma unroll
  for (int o = 32; o; o >>= 1) s += __shfl_down(s, o);
  if ((tid & 63) == 0) red[tid >> 6] = s;
  __syncthreads();
  float mu = (red[0] + red[1] + red[2] + red[3]) * (1.0f / 512.0f);
  __syncthreads();
  float da = a - mu, db = b2 - mu;
  float q = da * da + db * db;
#pragma unroll
  for (int o = 32; o; o >>= 1) q += __shfl_down(q, o);
  if ((tid & 63) == 0) red[tid >> 6] = q;
  __syncthreads();
  float var = (red[0] + red[1] + red[2] + red[3]) * (1.0f / 512.0f);
  float rs = rsqrtf(var + 1e-20f);
  float o1 = da * rs * ldf(g, goff + tid, fl)       + ldf(be, goff + tid, fl);
  float o2 = db * rs * ldf(g, goff + tid + 256, fl) + ldf(be, goff + tid + 256, fl);
  xfo[base + tid]       = o1;
  xfo[base + tid + 256] = o2;
  if (SPLIT) {
    bf16 h1 = (bf16)o1, h2 = (bf16)o2;
    xh[base + tid]       = h1; xl[base + tid]       = (bf16)(o1 - (float)h1);
    xh[base + tid + 256] = h2; xl[base + tid + 256] = (bf16)(o2 - (float)h2);
  }
}

// =====================================================================
extern "C" void kernel_launch(void* const* d_in, const int* in_sizes, int n_in,
                              void* d_out, int out_size, void* d_ws, size_t ws_size,
                              hipStream_t stream)
{
  (void)in_sizes; (void)n_in; (void)out_size; (void)ws_size;
  const void* x_in   = d_in[0];
  const void* enc_in = d_in[1];
  const int*  tokens = (const int*)d_in[2];
  const void* sWqkv = d_in[3];
  const void* sbqkv = d_in[4];
  const void* sWo   = d_in[5];
  const void* sbo   = d_in[6];
  const void* cWqkv = d_in[7];
  const void* cbqkv = d_in[8];
  const void* cWo   = d_in[9];
  const void* cbo   = d_in[10];
  const void* fc1w  = d_in[11];
  const void* fc1b  = d_in[12];
  const void* fc2w  = d_in[13];
  const void* fc2b  = d_in[14];
  const void* ln1g  = d_in[15];
  const void* ln1b  = d_in[16];
  const void* ln2g  = d_in[17];
  const void* ln2b  = d_in[18];
  const void* ln3g  = d_in[19];
  const void* ln3b  = d_in[20];

  char* ws = (char*)d_ws;
  size_t off = 0;
  auto alloc = [&](size_t bytes) -> char* {
    char* p = ws + off;
    off += (bytes + 255) & ~(size_t)255;
    return p;
  };
  int*   flags   = (int*)  alloc(256);
  float* mmf     = (float*)alloc(256);
  float* vsum    = (float*)alloc(1024 * 4);
  float* partial = (float*)alloc(4096);
  float* term    = (float*)alloc(1024 * 4);
  float* xf      = (float*)alloc((size_t)ROWS * CE * 4);          //  8 MiB residual
  bf16*  xh      = (bf16*) alloc((size_t)ROWS * CE * 2);          //  4 MiB
  bf16*  xl      = (bf16*) alloc((size_t)ROWS * CE * 2);          //  4 MiB
  float* qkv     = (float*)alloc((size_t)ROWS * 2048 * 4);        // 32 MiB (proj fp32 / h split)
  bf16*  pvh     = (bf16*) alloc((size_t)ROWS * CE * 2);          //  4 MiB
  bf16*  pvl     = (bf16*) alloc((size_t)ROWS * CE * 2);          //  4 MiB
  float* pblk    = (float*)alloc((size_t)ROWS * CE * 4 * 4);      // 32 MiB split-K partials
  bf16*  khb     = (bf16*) alloc((size_t)16 * T_SEQ * 64 * 2);    //  4 MiB
  bf16*  klb     = (bf16*) alloc((size_t)16 * T_SEQ * 64 * 2);    //  4 MiB
  bf16*  vth     = (bf16*) alloc((size_t)16 * 64 * T_SEQ * 2);    //  4 MiB
  bf16*  vtl     = (bf16*) alloc((size_t)16 * 64 * T_SEQ * 2);    //  4 MiB
  float* vcs     = (float*)alloc((size_t)16 * 32 * 64 * 4);       // 128 KiB
  bf16*  wh      = (bf16*) alloc((size_t)18874368 * 2);           // 36 MiB (fp32-storage fallback)
  bf16*  wl      = (bf16*) alloc((size_t)18874368 * 2);           // 36 MiB
  bf16* hh = (bf16*)qkv;                     // h split aliases qkv
  bf16* hl = (bf16*)qkv + (size_t)ROWS * 2048;
  const long long PS_FULL = (long long)ROWS * CE;

  sniff<<<1, 256, 0, stream>>>((const u16*)x_in, tokens, flags);
  posembed<<<ROWS, 256, 0, stream>>>(x_in, tokens, flags, xf, xh, xl);
  wprep<<<dim3(1024, 7), 256, 0, stream>>>(sWqkv, sWo, cWqkv, cWo, fc1w, fc2w, enc_in,
                                           wh, wl, flags);   // early-exits on bf16 storage

  for (int l = 0; l < 4; l++) {
    // ---------------- self-attention ----------------
    gemm_bb<0, true><<<384, 256, 0, stream>>>(
        xh, xl, xh, wh, wl, 0,
        sWqkv, (long long)l * 786432, O_SQ + (long long)l * 786432,
        sbqkv, (size_t)l * 1536, flags,
        qkv, nullptr, nullptr, 1536, 512, 512, 12, 12, 0);
    prep_kv<<<dim3(16, 32), 256, 0, stream>>>(qkv, 1536, 512, 1024, khb, klb, vth, vtl, vcs);
    fattn<true><<<512, 256, 0, stream>>>(qkv, 1536, 0, khb, klb, vth, vtl, partial, pvh, pvl);
    reduce_mm<<<1, 512, 0, stream>>>(partial, vcs, mmf, vsum);
    wo_term<<<8, 256, 0, stream>>>(mmf, vsum, sWo, (size_t)l * 262144, sbo, (size_t)l * 512,
                                   flags, term);
    gemm_bb<0, false><<<512, 256, 0, stream>>>(       // Wo raw-PV, split-K4
        pvh, pvl, pvh, wh, wl, 0,
        sWo, (long long)l * 262144, O_SWO + (long long)l * 262144,
        sbo, 0, flags,
        pblk, nullptr, nullptr, 512, 512, 128, 4, 4, PS_FULL);
    ln_sum<4, true, true><<<ROWS, 256, 0, stream>>>(
        xf, pblk, PS_FULL, ln1g, ln1b, (size_t)l * 512, flags, mmf, term, xf, xh, xl);

    // ---------------- cross-attention (merged q|kv, N=1536) ----------------
    gemm_bb<0, true><<<384, 256, 0, stream>>>(
        xh, xl, enc_in, wh, wl, O_E,
        cWqkv, (long long)l * 786432, O_CQ + (long long)l * 786432,
        cbqkv, (size_t)l * 1536, flags,
        qkv, nullptr, nullptr, 1536, 512, 512, 12, 4, 0);
    prep_kv<<<dim3(16, 32), 256, 0, stream>>>(qkv, 1536, 512, 1024, khb, klb, vth, vtl, vcs);
    fattn<false><<<512, 256, 0, stream>>>(qkv, 1536, 0, khb, klb, vth, vtl, partial, pvh, pvl);
    reduce_mm<<<1, 512, 0, stream>>>(partial, vcs, mmf, vsum);
    wo_term<<<8, 256, 0, stream>>>(mmf, vsum, cWo, (size_t)l * 262144, cbo, (size_t)l * 512,
                                   flags, term);
    gemm_bb<0, false><<<512, 256, 0, stream>>>(       // cWo raw-PV, split-K4
        pvh, pvl, pvh, wh, wl, 0,
        cWo, (long long)l * 262144, O_CWO + (long long)l * 262144,
        cbo, 0, flags,
        pblk, nullptr, nullptr, 512, 512, 128, 4, 4, PS_FULL);
    ln_sum<4, true, true><<<ROWS, 256, 0, stream>>>(
        xf, pblk, PS_FULL, ln2g, ln2b, (size_t)l * 512, flags, mmf, term, xf, xh, xl);

    // ---------------- FFN ----------------
    gemm_bb<1, true><<<512, 256, 0, stream>>>(        // fc1 -> relu -> h split
        xh, xl, xh, wh, wl, 0,
        fc1w, (long long)l * 1048576, O_F1 + (long long)l * 1048576,
        fc1b, (size_t)l * 2048, flags,
        nullptr, hh, hl, 2048, 512, 512, 16, 16, 0);
    gemm_bb<0, true><<<512, 256, 0, stream>>>(        // fc2 split-K4
        hh, hl, hh, wh, wl, 0,
        fc2w, (long long)l * 1048576, O_F2 + (long long)l * 1048576,
        fc2b, (size_t)l * 512, flags,
        pblk, nullptr, nullptr, 512, 2048, 512, 4, 4, PS_FULL);
    if (l == 3) {
      ln_sum<4, false, false><<<ROWS, 256, 0, stream>>>(
          xf, pblk, PS_FULL, ln3g, ln3b, (size_t)l * 512, flags, nullptr, nullptr,
          (float*)d_out, nullptr, nullptr);
    } else {
      ln_sum<4, false, true><<<ROWS, 256, 0, stream>>>(
          xf, pblk, PS_FULL, ln3g, ln3b, (size_t)l * 512, flags, nullptr, nullptr,
          xf, xh, xl);
    }
  }
}

// Round 8
// 2299.018 us; speedup vs baseline: 1.3980x; 1.3046x over previous
//
#include <hip/hip_runtime.h>
#include <math.h>

typedef __bf16 bf16;
typedef unsigned short u16;
typedef unsigned int u32;
typedef __bf16 bf16x8 __attribute__((ext_vector_type(8)));
typedef float f32x4 __attribute__((ext_vector_type(4)));

#define T_SEQ 2048
#define NB    2
#define CE    512
#define HD    64
#define ROWS  4096
#define LDT   40   // GEMM LDS stride (32+8)
#define LDA   72   // attn LDS stride (64+8)

#define MFMA16(a,b,c) __builtin_amdgcn_mfma_f32_16x16x32_bf16((a),(b),(c),0,0,0)

// bijective XCD-chunked swizzle (m204)
static __device__ __forceinline__ int xcd_swz(int id, int n) {
  int q = n >> 3, r = n & 7;
  int x = id & 7, o = id >> 3;
  return (x < r) ? (x * (q + 1) + o) : (r * (q + 1) + (x - r) * q + o);
}

static __device__ __forceinline__ float ldf(const void* src, size_t eoff, bool f32) {
  return f32 ? ((const float*)src)[eoff] : (float)((const bf16*)src)[eoff];
}

// monotone float<->uint encoding for atomicMin/Max on floats
static __device__ __forceinline__ u32 fenc(float f) {
  u32 u = __float_as_uint(f);
  return (u & 0x80000000u) ? ~u : (u | 0x80000000u);
}
static __device__ __forceinline__ float fdec(u32 u) {
  u32 v = (u & 0x80000000u) ? (u & 0x7fffffffu) : ~u;
  return __uint_as_float(v);
}

// =====================================================================
// Sniffer: flags[0]=fp32 storage; flags[1]=tokens int64;
// flags[3]=enc lo nonzero (probe); flags[4]=weight lo nonzero (probe)
// =====================================================================
__global__ __launch_bounds__(256) void sniff(const u16* __restrict__ xs,
                                             const int* __restrict__ toks,
                                             int* __restrict__ flags)
{
  const int tid = threadIdx.x;
  int crazy = 0, ze = 0;
  for (int i = tid; i < 4096; i += 256) {
    int e = (xs[i] >> 7) & 0xFF;
    if (e >= 141) crazy++;
    if (((i & 1) == 0) && (xs[i] == 0)) ze++;
  }
  int zc = 0;
  for (int i = tid; i < 1024; i += 256)
    if (toks[2 * i + 1] == 0) zc++;
  __shared__ int r1[4], r2[4], r3[4];
#pragma unroll
  for (int o = 32; o; o >>= 1) {
    crazy += __shfl_down(crazy, o); ze += __shfl_down(ze, o); zc += __shfl_down(zc, o);
  }
  if ((tid & 63) == 0) { r1[tid >> 6] = crazy; r2[tid >> 6] = ze; r3[tid >> 6] = zc; }
  __syncthreads();
  if (tid == 0) {
    int c = r1[0] + r1[1] + r1[2] + r1[3];
    int z = r2[0] + r2[1] + r2[2] + r2[3];
    int t = r3[0] + r3[1] + r3[2] + r3[3];
    flags[0] = (z > 1500 || c > 64) ? 1 : 0;
    flags[1] = (t > 900) ? 1 : 0;
    flags[3] = 0;
    flags[4] = 0;
  }
}

// =====================================================================
// Read-only probe: does any weight (y<6) / enc (y==6) element have a
// nonzero bf16 low-order part? Only meaningful for fp32 storage.
// grid (128, 7), grid-stride float4.
// =====================================================================
__global__ __launch_bounds__(256) void probe_lo(const void* w0, const void* w1, const void* w2,
                                                const void* w3, const void* w4, const void* w5,
                                                const void* w6,
                                                int* __restrict__ flags)
{
  if (flags[0] == 0) return;       // bf16 storage: raw tensors used directly, no lo
  const int m = blockIdx.y;
  const void* srcs[7] = {w0, w1, w2, w3, w4, w5, w6};
  const int sizes[7]  = {3145728, 1048576, 3145728, 1048576, 4194304, 4194304, 2097152};
  const float4* p = (const float4*)srcs[m];
  const int n4 = sizes[m] >> 2;
  bool nz = false;
  for (int i = blockIdx.x * 256 + threadIdx.x; i < n4; i += 128 * 256) {
    float4 v = p[i];
    nz = nz || (v.x != (float)(bf16)v.x) || (v.y != (float)(bf16)v.y)
            || (v.z != (float)(bf16)v.z) || (v.w != (float)(bf16)v.w);
  }
  unsigned long long mv = __ballot(nz);
  if ((threadIdx.x & 63) == 0 && mv)
    atomicOr(&flags[(m == 6) ? 3 : 4], 1);
}

// =====================================================================
// Positional embedding: xf fp32 + xh/xl split
// =====================================================================
__global__ __launch_bounds__(256) void posembed(const void* __restrict__ xsrc,
                                                const int* __restrict__ toks,
                                                const int* __restrict__ flags,
                                                float* __restrict__ xf,
                                                bf16* __restrict__ xh, bf16* __restrict__ xl)
{
  const bool f32 = flags[0] != 0;
  const bool tok64 = flags[1] != 0;
  const int row = blockIdx.x;
  const int t = row >> 1, b = row & 1;
  const int tix = b * T_SEQ + t;
  const int tok = tok64 ? toks[2 * tix] : toks[tix];
  const int p = (tok != 0) ? (t + 1) : 0;
  const float kf = -0.0361193740f;
  for (int c = threadIdx.x; c < CE; c += 256) {
    float pe = 0.0f;
    if (p != 0) {
      int i = (c < 256) ? c : (c - 256);
      float freq = expf((float)i * kf);
      float ang = (float)p * freq;
      pe = (c < 256) ? sinf(ang) : cosf(ang);
    }
    float v = ldf(xsrc, (size_t)row * CE + c, f32) + pe;
    size_t o = (size_t)row * CE + c;
    xf[o] = v;
    bf16 hi = (bf16)v;
    xh[o] = hi; xl[o] = (bf16)(v - (float)hi);
  }
}

// =====================================================================
// MFMA GEMM, 128x64 tile, 4 waves (2Mx2N), single LDS buffer + write-late
// reg prefetch (T14), 1D grid + XCD swizzle, split-K.
// A (bx<nbxA): pre-split activation hi/lo (always 2 streams).
// A (bx>=nbxA): raw enc — fp32 storage: in-reg cvt hi (+lo if flags[3]);
//               bf16 storage: direct copy.
// B: raw weights — fp32 storage: in-reg cvt hi (+lo if flags[4]);
//    bf16 storage: direct copy.
// OUTM 0: fp32 out (+bias at z0 if BIAS); OUTM 1: relu+bias -> bf16 hi/lo.
// =====================================================================
template<int OUTM, bool BIAS>
__global__ __launch_bounds__(256) void gemm_bb(const bf16* __restrict__ A1h, const bf16* __restrict__ A1l,
                                               const void* __restrict__ A2,
                                               const void* __restrict__ Braw, long long bOff,
                                               const void* __restrict__ bias, size_t biasOff,
                                               const int* __restrict__ flags,
                                               float* __restrict__ Cf,
                                               bf16* __restrict__ Coh, bf16* __restrict__ Col,
                                               int N, int K, int kspan, int nbx, int nbxA,
                                               long long partStride)
{
  __shared__ __align__(16) bf16 Ah[128 * LDT];
  __shared__ __align__(16) bf16 Al[128 * LDT];
  __shared__ __align__(16) bf16 Bh[64 * LDT];
  __shared__ __align__(16) bf16 Bl[64 * LDT];
  const int id = xcd_swz((int)blockIdx.x, (int)gridDim.x);
  const int per_z = nbx * 32;
  const int zz = id / per_z;
  const int rem = id - zz * per_z;
  const int by = rem / nbx, bx = rem - by * nbx;
  const bool bfl = flags[0] != 0;
  const bool blo = bfl && (flags[4] != 0);
  const bool aSplit = (bx < nbxA);
  const bool a2lo = bfl && (flags[3] != 0);
  const bool alo = aSplit ? true : a2lo;
  const int tid = threadIdx.x;
  const int m0 = by * 128, n0 = bx * 64;
  const int srA = tid >> 1, skA = (tid & 1) * 16;   // 128 x 32 A-slab
  const int srB = tid >> 2, skB = (tid & 3) * 8;    //  64 x 32 B-slab
  const int wid = tid >> 6, lane = tid & 63;
  const int wm = (wid >> 1) * 64, wn = (wid & 1) * 32;
  const int fr = lane & 15, fk = (lane >> 4) * 8;
  const int kb = zz * kspan;
  const int ke = (kb + kspan < K) ? (kb + kspan) : K;
  f32x4 acc[4][2] = {};

  uint4 ra0, ra1, ra2, ra3, rb0, rb1;
  auto loadA = [&](int k0) {
    size_t g = (size_t)(m0 + srA) * K + k0 + skA;
    if (aSplit) {
      const uint4* p = (const uint4*)(A1h + g); ra0 = p[0]; ra1 = p[1];
      const uint4* q = (const uint4*)(A1l + g); ra2 = q[0]; ra3 = q[1];
    } else if (bfl) {
      const uint4* p = (const uint4*)((const float*)A2 + g);
      ra0 = p[0]; ra1 = p[1]; ra2 = p[2]; ra3 = p[3];
    } else {
      const uint4* p = (const uint4*)((const bf16*)A2 + g); ra0 = p[0]; ra1 = p[1];
    }
  };
  auto loadB = [&](int k0) {
    size_t g = (size_t)bOff + (size_t)(n0 + srB) * K + k0 + skB;
    if (bfl) {
      const uint4* p = (const uint4*)((const float*)Braw + g); rb0 = p[0]; rb1 = p[1];
    } else {
      rb0 = *(const uint4*)((const bf16*)Braw + g);
    }
  };
  auto storeA = [&]() {
    if (aSplit) {
      *(uint4*)&Ah[srA * LDT + skA]     = ra0;
      *(uint4*)&Ah[srA * LDT + skA + 8] = ra1;
      *(uint4*)&Al[srA * LDT + skA]     = ra2;
      *(uint4*)&Al[srA * LDT + skA + 8] = ra3;
    } else if (bfl) {
      const float* f = (const float*)&ra0;   // ra0..ra3 contiguous? not guaranteed — copy
      float v[16];
      const float* f0 = (const float*)&ra0; const float* f1 = (const float*)&ra1;
      const float* f2 = (const float*)&ra2; const float* f3 = (const float*)&ra3;
#pragma unroll
      for (int q = 0; q < 4; q++) { v[q] = f0[q]; v[4+q] = f1[q]; v[8+q] = f2[q]; v[12+q] = f3[q]; }
      (void)f;
      bf16x8 h0, h1;
#pragma unroll
      for (int q = 0; q < 8; q++) { h0[q] = (bf16)v[q]; h1[q] = (bf16)v[8+q]; }
      *(bf16x8*)&Ah[srA * LDT + skA]     = h0;
      *(bf16x8*)&Ah[srA * LDT + skA + 8] = h1;
      if (a2lo) {
        bf16x8 l0, l1;
#pragma unroll
        for (int q = 0; q < 8; q++) {
          l0[q] = (bf16)(v[q]   - (float)h0[q]);
          l1[q] = (bf16)(v[8+q] - (float)h1[q]);
        }
        *(bf16x8*)&Al[srA * LDT + skA]     = l0;
        *(bf16x8*)&Al[srA * LDT + skA + 8] = l1;
      }
    } else {
      *(uint4*)&Ah[srA * LDT + skA]     = ra0;
      *(uint4*)&Ah[srA * LDT + skA + 8] = ra1;
    }
  };
  auto storeB = [&]() {
    if (bfl) {
      float v[8];
      const float* f0 = (const float*)&rb0; const float* f1 = (const float*)&rb1;
#pragma unroll
      for (int q = 0; q < 4; q++) { v[q] = f0[q]; v[4+q] = f1[q]; }
      bf16x8 h0;
#pragma unroll
      for (int q = 0; q < 8; q++) h0[q] = (bf16)v[q];
      *(bf16x8*)&Bh[srB * LDT + skB] = h0;
      if (blo) {
        bf16x8 l0;
#pragma unroll
        for (int q = 0; q < 8; q++) l0[q] = (bf16)(v[q] - (float)h0[q]);
        *(bf16x8*)&Bl[srB * LDT + skB] = l0;
      }
    } else {
      *(uint4*)&Bh[srB * LDT + skB] = rb0;
    }
  };

  loadA(kb); loadB(kb);
  for (int k0 = kb; k0 < ke; k0 += 32) {
    __syncthreads();                  // previous MFMA done reading LDS
    storeA(); storeB();
    __syncthreads();                  // LDS staged
    if (k0 + 32 < ke) { loadA(k0 + 32); loadB(k0 + 32); }   // rides under MFMA
    bf16x8 ah[4], bh2[2];
#pragma unroll
    for (int i = 0; i < 4; i++) ah[i] = *(const bf16x8*)&Ah[(wm + i*16 + fr) * LDT + fk];
#pragma unroll
    for (int j = 0; j < 2; j++) bh2[j] = *(const bf16x8*)&Bh[(wn + j*16 + fr) * LDT + fk];
#pragma unroll
    for (int i = 0; i < 4; i++)
#pragma unroll
      for (int j = 0; j < 2; j++)
        acc[i][j] = MFMA16(ah[i], bh2[j], acc[i][j]);
    if (alo) {
      bf16x8 al[4];
#pragma unroll
      for (int i = 0; i < 4; i++) al[i] = *(const bf16x8*)&Al[(wm + i*16 + fr) * LDT + fk];
#pragma unroll
      for (int i = 0; i < 4; i++)
#pragma unroll
        for (int j = 0; j < 2; j++)
          acc[i][j] = MFMA16(al[i], bh2[j], acc[i][j]);
    }
    if (blo) {
      bf16x8 bl[2];
#pragma unroll
      for (int j = 0; j < 2; j++) bl[j] = *(const bf16x8*)&Bl[(wn + j*16 + fr) * LDT + fk];
#pragma unroll
      for (int i = 0; i < 4; i++)
#pragma unroll
        for (int j = 0; j < 2; j++)
          acc[i][j] = MFMA16(ah[i], bl[j], acc[i][j]);
    }
  }
  const int orow0 = m0 + wm + (lane >> 4) * 4;
  const int ocol0 = n0 + wn + (lane & 15);
  if (OUTM == 0) {
    float* Cp = Cf + (long long)zz * partStride;
    const bool addb = BIAS && (zz == 0);
#pragma unroll
    for (int j = 0; j < 2; j++) {
      int col = ocol0 + j * 16;
      float bv = addb ? ldf(bias, biasOff + col, flags[0] != 0) : 0.0f;
#pragma unroll
      for (int i = 0; i < 4; i++)
#pragma unroll
        for (int r = 0; r < 4; r++)
          Cp[(size_t)(orow0 + i * 16 + r) * N + col] = acc[i][j][r] + bv;
    }
  } else {
#pragma unroll
    for (int j = 0; j < 2; j++) {
      int col = ocol0 + j * 16;
      float bv = ldf(bias, biasOff + col, flags[0] != 0);
#pragma unroll
      for (int i = 0; i < 4; i++)
#pragma unroll
        for (int r = 0; r < 4; r++) {
          float vv = fmaxf(acc[i][j][r] + bv, 0.0f);
          bf16 hi = (bf16)vv;
          size_t o = (size_t)(orow0 + i * 16 + r) * N + col;
          Coh[o] = hi; Col[o] = (bf16)(vv - (float)hi);
        }
    }
  }
}

// =====================================================================
// Fused K/V prepass + mmf init: K split -> kh/kl [bh][s][64]; V
// transpose+split -> vth/vtl [bh][d][s]; per-chunk col sums vcs.
// =====================================================================
__global__ __launch_bounds__(256) void prep_kv(const float* __restrict__ base, int ld,
                                               int kofs0, int vofs0,
                                               bf16* __restrict__ kh, bf16* __restrict__ kl,
                                               bf16* __restrict__ vth, bf16* __restrict__ vtl,
                                               float* __restrict__ vcs,
                                               u32* __restrict__ mmf_u)
{
  __shared__ float ts[64 * 65];
  const int bh = blockIdx.x, s0 = blockIdx.y * 64;
  const int b = bh >> 3, hq = bh & 7;
  const int kofs = kofs0 + hq * HD, vofs = vofs0 + hq * HD;
  const int tid = threadIdx.x;
  if (tid == 0) { mmf_u[0] = 0xFFFFFFFFu; mmf_u[1] = 0u; }   // all blocks: same consts
#pragma unroll
  for (int it = 0; it < 16; ++it) {
    int idx = it * 256 + tid, r = idx >> 6, d = idx & 63;
    size_t rowb = (size_t)((s0 + r) * NB + b) * ld;
    float v = base[rowb + kofs + d];
    bf16 hi = (bf16)v;
    size_t o = ((size_t)bh * T_SEQ + s0 + r) * 64 + d;
    kh[o] = hi; kl[o] = (bf16)(v - (float)hi);
    ts[r * 65 + d] = base[rowb + vofs + d];
  }
  __syncthreads();
  const int d = tid >> 2, sseg = (tid & 3) * 16;
  bf16x8 hv0, lv0, hv1, lv1;
#pragma unroll
  for (int q = 0; q < 8; ++q) {
    float v0 = ts[(sseg + q) * 65 + d];
    float v1 = ts[(sseg + 8 + q) * 65 + d];
    bf16 h0 = (bf16)v0, h1 = (bf16)v1;
    hv0[q] = h0; lv0[q] = (bf16)(v0 - (float)h0);
    hv1[q] = h1; lv1[q] = (bf16)(v1 - (float)h1);
  }
  size_t o = ((size_t)bh * 64 + d) * T_SEQ + s0 + sseg;
  *(bf16x8*)&vth[o]     = hv0;
  *(bf16x8*)&vth[o + 8] = hv1;
  *(bf16x8*)&vtl[o]     = lv0;
  *(bf16x8*)&vtl[o + 8] = lv1;
  if (tid < 64) {
    float s = 0.0f;
    for (int j = 0; j < 64; ++j) s += ts[j * 65 + tid];
    vcs[((size_t)bh * 32 + blockIdx.y) * 64 + tid] = s;
  }
}

__device__ __forceinline__ int remap_ty(int ty) { return (ty < 16) ? ty : 47 - ty; }

// =====================================================================
// Fused attention: raw masked scores (3-term QK), global min/max via
// encoded atomics, raw PV (3-term) -> pv bf16 hi/lo split.
// =====================================================================
template<bool MASK>
__global__ __launch_bounds__(256) void fattn(const float* __restrict__ qbase, int qld, int qofs0,
                                             const bf16* __restrict__ kh, const bf16* __restrict__ kl,
                                             const bf16* __restrict__ vth, const bf16* __restrict__ vtl,
                                             u32* __restrict__ mmf_u,
                                             bf16* __restrict__ pvh, bf16* __restrict__ pvl)
{
  __shared__ __align__(16) bf16 Qh[64 * LDA], Ql[64 * LDA];
  __shared__ __align__(16) bf16 Kh[64 * LDA], Kl[64 * LDA];
  __shared__ __align__(16) bf16 Vh[64 * LDA], Vl[64 * LDA];
  __shared__ __align__(16) bf16 Ph[64 * LDA], Pl[64 * LDA];
  __shared__ float rn[4], rx[4];
  const int id = xcd_swz((int)blockIdx.x, 512);
  const int bh = id >> 5;
  const int tyr = remap_ty(id & 31);
  const int t0 = tyr * 64;
  const int b = bh >> 3, hq = bh & 7;
  const int qofs = qofs0 + hq * HD;
  const int tid = threadIdx.x;
#pragma unroll
  for (int it = 0; it < 16; ++it) {
    int idx = it * 256 + tid, r = idx >> 6, d = idx & 63;
    float v = qbase[(size_t)((t0 + r) * NB + b) * qld + qofs + d] * 0.125f;
    bf16 hi = (bf16)v;
    Qh[r * LDA + d] = hi; Ql[r * LDA + d] = (bf16)(v - (float)hi);
  }
  const int wid = tid >> 6, lane = tid & 63;
  const int wm_ = (wid >> 1) * 32, wn_ = (wid & 1) * 32;
  const int fr = lane & 15, fko = (lane >> 4) * 8;
  const int crr = (lane >> 4) * 4, crc = lane & 15;
  const int cr = tid >> 2, cseg = (tid & 3) * 16;
  float mn = 1e30f, mx = -1e30f;
  f32x4 o4[2][2] = {};
  const int nch = MASK ? (tyr + 1) : 32;
  for (int sc = 0; sc < nch; ++sc) {
    const int s0 = sc * 64;
    __syncthreads();
    {
      size_t go = ((size_t)bh * T_SEQ + s0 + cr) * 64 + cseg;
      *(bf16x8*)&Kh[cr * LDA + cseg]     = *(const bf16x8*)&kh[go];
      *(bf16x8*)&Kh[cr * LDA + cseg + 8] = *(const bf16x8*)&kh[go + 8];
      *(bf16x8*)&Kl[cr * LDA + cseg]     = *(const bf16x8*)&kl[go];
      *(bf16x8*)&Kl[cr * LDA + cseg + 8] = *(const bf16x8*)&kl[go + 8];
      size_t gv = ((size_t)bh * 64 + cr) * T_SEQ + s0 + cseg;
      *(bf16x8*)&Vh[cr * LDA + cseg]     = *(const bf16x8*)&vth[gv];
      *(bf16x8*)&Vh[cr * LDA + cseg + 8] = *(const bf16x8*)&vth[gv + 8];
      *(bf16x8*)&Vl[cr * LDA + cseg]     = *(const bf16x8*)&vtl[gv];
      *(bf16x8*)&Vl[cr * LDA + cseg + 8] = *(const bf16x8*)&vtl[gv + 8];
    }
    __syncthreads();
    f32x4 a4[2][2] = {};
#pragma unroll
    for (int ks = 0; ks < 2; ++ks) {
      bf16x8 aH[2], aL[2], bH[2], bL[2];
#pragma unroll
      for (int i = 0; i < 2; ++i) {
        aH[i] = *(const bf16x8*)&Qh[(wm_ + i*16 + fr) * LDA + ks*32 + fko];
        aL[i] = *(const bf16x8*)&Ql[(wm_ + i*16 + fr) * LDA + ks*32 + fko];
        bH[i] = *(const bf16x8*)&Kh[(wn_ + i*16 + fr) * LDA + ks*32 + fko];
        bL[i] = *(const bf16x8*)&Kl[(wn_ + i*16 + fr) * LDA + ks*32 + fko];
      }
#pragma unroll
      for (int i = 0; i < 2; ++i)
#pragma unroll
        for (int j = 0; j < 2; ++j) {
          a4[i][j] = MFMA16(aH[i], bH[j], a4[i][j]);
          a4[i][j] = MFMA16(aL[i], bH[j], a4[i][j]);
          a4[i][j] = MFMA16(aH[i], bL[j], a4[i][j]);
        }
    }
#pragma unroll
    for (int i = 0; i < 2; ++i)
#pragma unroll
      for (int j = 0; j < 2; ++j)
#pragma unroll
        for (int r = 0; r < 4; ++r) {
          int tl = wm_ + i*16 + crr + r;
          int sl = wn_ + j*16 + crc;
          float w = a4[i][j][r];
          if (MASK && (s0 + sl) > (t0 + tl)) w = 0.0f;
          mn = fminf(mn, w); mx = fmaxf(mx, w);
          bf16 wh = (bf16)w;
          Ph[tl * LDA + sl] = wh;
          Pl[tl * LDA + sl] = (bf16)(w - (float)wh);
        }
    __syncthreads();
#pragma unroll
    for (int ks = 0; ks < 2; ++ks) {
      bf16x8 pH[2], pL[2], vH[2], vL[2];
#pragma unroll
      for (int i = 0; i < 2; ++i) {
        pH[i] = *(const bf16x8*)&Ph[(wm_ + i*16 + fr) * LDA + ks*32 + fko];
        pL[i] = *(const bf16x8*)&Pl[(wm_ + i*16 + fr) * LDA + ks*32 + fko];
        vH[i] = *(const bf16x8*)&Vh[(wn_ + i*16 + fr) * LDA + ks*32 + fko];
        vL[i] = *(const bf16x8*)&Vl[(wn_ + i*16 + fr) * LDA + ks*32 + fko];
      }
#pragma unroll
      for (int i = 0; i < 2; ++i)
#pragma unroll
        for (int j = 0; j < 2; ++j) {
          o4[i][j] = MFMA16(pH[i], vH[j], o4[i][j]);
          o4[i][j] = MFMA16(pL[i], vH[j], o4[i][j]);
          o4[i][j] = MFMA16(pH[i], vL[j], o4[i][j]);
        }
    }
  }
#pragma unroll
  for (int i = 0; i < 2; ++i)
#pragma unroll
    for (int j = 0; j < 2; ++j)
#pragma unroll
      for (int r = 0; r < 4; ++r) {
        int tl = wm_ + i*16 + crr + r;
        int dl = wn_ + j*16 + crc;
        float val = o4[i][j][r];
        bf16 hi = (bf16)val;
        size_t o = (size_t)((t0 + tl) * NB + b) * CE + hq * HD + dl;
        pvh[o] = hi; pvl[o] = (bf16)(val - (float)hi);
      }
#pragma unroll
  for (int o = 32; o; o >>= 1) { mn = fminf(mn, __shfl_down(mn, o)); mx = fmaxf(mx, __shfl_down(mx, o)); }
  if (lane == 0) { rn[wid] = mn; rx[wid] = mx; }
  __syncthreads();
  if (tid == 0) {
    float bmn = fminf(fminf(rn[0], rn[1]), fminf(rn[2], rn[3]));
    float bmx = fmaxf(fmaxf(rx[0], rx[1]), fmaxf(rx[2], rx[3]));
    atomicMin(&mmf_u[0], fenc(bmn));
    atomicMax(&mmf_u[1], fenc(bmx));
  }
}

// =====================================================================
// term[b*512+c] = -(mn*inv)*(vsum[b]@Wo[c]) + bo[c]
// grid 64 x 256; 16 outputs/block, 16 threads/output; vsum from vcs in LDS
// =====================================================================
__global__ __launch_bounds__(256) void wo_term(const u32* __restrict__ mmf_u,
                                               const float* __restrict__ vcs,
                                               const void* __restrict__ Wo, size_t woOff,
                                               const void* __restrict__ bo, size_t boOff,
                                               const int* __restrict__ flags,
                                               float* __restrict__ term)
{
  __shared__ float vs[512];
  const bool fl = flags[0] != 0;
  const int tid = threadIdx.x;
  const float mn = fdec(mmf_u[0]);
  const float inv = 1.0f / (fdec(mmf_u[1]) - mn);
  const float cmn = mn * inv;
  const int b = blockIdx.x >> 5;
  for (int k = tid; k < 512; k += 256) {
    int h = k >> 6, d = k & 63;
    float s = 0.0f;
#pragma unroll
    for (int ch = 0; ch < 32; ++ch)
      s += vcs[(size_t)((b * 8 + h) * 32 + ch) * 64 + d];
    vs[k] = s;
  }
  __syncthreads();
  const int out = blockIdx.x * 16 + (tid >> 4);
  const int c = out & 511;
  const int k0 = (tid & 15) * 32;
  float s = 0.0f;
#pragma unroll 8
  for (int k = 0; k < 32; ++k)
    s += vs[k0 + k] * ldf(Wo, woOff + (size_t)c * 512 + k0 + k, fl);
  s += __shfl_down(s, 8); s += __shfl_down(s, 4); s += __shfl_down(s, 2); s += __shfl_down(s, 1);
  if ((tid & 15) == 0)
    term[out] = -cmn * s + ldf(bo, boOff + c, fl);
}

// =====================================================================
// LayerNorm(res + [AFF? inv*sum(NP partials)+term : sum(NP partials)])
// =====================================================================
template<int NP, bool AFF, bool SPLIT>
__global__ __launch_bounds__(256) void ln_sum(const float* __restrict__ res,
                                              const float* __restrict__ p, long long pstride,
                                              const void* __restrict__ g, const void* __restrict__ be,
                                              size_t goff, const int* __restrict__ flags,
                                              const u32* __restrict__ mmf_u,
                                              const float* __restrict__ term,
                                              float* __restrict__ xfo,
                                              bf16* __restrict__ xh, bf16* __restrict__ xl)
{
  __shared__ float red[4];
  const bool fl = flags[0] != 0;
  const int tid = threadIdx.x;
  const size_t base = (size_t)blockIdx.x * CE;
  float pa = 0.0f, pb = 0.0f;
#pragma unroll
  for (int k = 0; k < NP; k++) {
    pa += p[(long long)k * pstride + base + tid];
    pb += p[(long long)k * pstride + base + tid + 256];
  }
  float a, b2;
  if (AFF) {
    const float mnv = fdec(mmf_u[0]);
    const float inv = 1.0f / (fdec(mmf_u[1]) - mnv);
    const int b = blockIdx.x & 1;
    a  = res[base + tid]       + inv * pa + term[b * 512 + tid];
    b2 = res[base + tid + 256] + inv * pb + term[b * 512 + tid + 256];
  } else {
    a  = res[base + tid]       + pa;
    b2 = res[base + tid + 256] + pb;
  }
  float s = a + b2;
#pragma unroll
  for (int o = 32; o; o >>= 1) s += __shfl_down(s, o);
  if ((tid & 63) == 0) red[tid >> 6] = s;
  __syncthreads();
  float mu = (red[0] + red[1] + red[2] + red[3]) * (1.0f / 512.0f);
  __syncthreads();
  float da = a - mu, db = b2 - mu;
  float q = da * da + db * db;
#pragma unroll
  for (int o = 32; o; o >>= 1) q += __shfl_down(q, o);
  if ((tid & 63) == 0) red[tid >> 6] = q;
  __syncthreads();
  float var = (red[0] + red[1] + red[2] + red[3]) * (1.0f / 512.0f);
  float rs = rsqrtf(var + 1e-20f);
  float o1 = da * rs * ldf(g, goff + tid, fl)       + ldf(be, goff + tid, fl);
  float o2 = db * rs * ldf(g, goff + tid + 256, fl) + ldf(be, goff + tid + 256, fl);
  xfo[base + tid]       = o1;
  xfo[base + tid + 256] = o2;
  if (SPLIT) {
    bf16 h1 = (bf16)o1, h2 = (bf16)o2;
    xh[base + tid]       = h1; xl[base + tid]       = (bf16)(o1 - (float)h1);
    xh[base + tid + 256] = h2; xl[base + tid + 256] = (bf16)(o2 - (float)h2);
  }
}

// =====================================================================
extern "C" void kernel_launch(void* const* d_in, const int* in_sizes, int n_in,
                              void* d_out, int out_size, void* d_ws, size_t ws_size,
                              hipStream_t stream)
{
  (void)in_sizes; (void)n_in; (void)out_size; (void)ws_size;
  const void* x_in   = d_in[0];
  const void* enc_in = d_in[1];
  const int*  tokens = (const int*)d_in[2];
  const void* sWqkv = d_in[3];
  const void* sbqkv = d_in[4];
  const void* sWo   = d_in[5];
  const void* sbo   = d_in[6];
  const void* cWqkv = d_in[7];
  const void* cbqkv = d_in[8];
  const void* cWo   = d_in[9];
  const void* cbo   = d_in[10];
  const void* fc1w  = d_in[11];
  const void* fc1b  = d_in[12];
  const void* fc2w  = d_in[13];
  const void* fc2b  = d_in[14];
  const void* ln1g  = d_in[15];
  const void* ln1b  = d_in[16];
  const void* ln2g  = d_in[17];
  const void* ln2b  = d_in[18];
  const void* ln3g  = d_in[19];
  const void* ln3b  = d_in[20];

  char* ws = (char*)d_ws;
  size_t off = 0;
  auto alloc = [&](size_t bytes) -> char* {
    char* p = ws + off;
    off += (bytes + 255) & ~(size_t)255;
    return p;
  };
  int*   flags   = (int*)  alloc(256);
  u32*   mmf_u   = (u32*)  alloc(256);
  float* term    = (float*)alloc(1024 * 4);
  float* xf      = (float*)alloc((size_t)ROWS * CE * 4);          //  8 MiB residual
  bf16*  xh      = (bf16*) alloc((size_t)ROWS * CE * 2);          //  4 MiB
  bf16*  xl      = (bf16*) alloc((size_t)ROWS * CE * 2);          //  4 MiB
  float* qkv     = (float*)alloc((size_t)ROWS * 2048 * 4);        // 32 MiB (proj fp32 / h split)
  bf16*  pvh     = (bf16*) alloc((size_t)ROWS * CE * 2);          //  4 MiB
  bf16*  pvl     = (bf16*) alloc((size_t)ROWS * CE * 2);          //  4 MiB
  float* pblk    = (float*)alloc((size_t)ROWS * CE * 4 * 4);      // 32 MiB split-K partials
  bf16*  khb     = (bf16*) alloc((size_t)16 * T_SEQ * 64 * 2);    //  4 MiB
  bf16*  klb     = (bf16*) alloc((size_t)16 * T_SEQ * 64 * 2);    //  4 MiB
  bf16*  vth     = (bf16*) alloc((size_t)16 * 64 * T_SEQ * 2);    //  4 MiB
  bf16*  vtl     = (bf16*) alloc((size_t)16 * 64 * T_SEQ * 2);    //  4 MiB
  float* vcs     = (float*)alloc((size_t)16 * 32 * 64 * 4);       // 128 KiB
  bf16* hh = (bf16*)qkv;                     // h split aliases qkv
  bf16* hl = (bf16*)qkv + (size_t)ROWS * 2048;
  const long long PS_FULL = (long long)ROWS * CE;

  sniff<<<1, 256, 0, stream>>>((const u16*)x_in, tokens, flags);
  probe_lo<<<dim3(128, 7), 256, 0, stream>>>(sWqkv, sWo, cWqkv, cWo, fc1w, fc2w, enc_in, flags);
  posembed<<<ROWS, 256, 0, stream>>>(x_in, tokens, flags, xf, xh, xl);

  for (int l = 0; l < 4; l++) {
    // ---------------- self-attention ----------------
    gemm_bb<0, true><<<768, 256, 0, stream>>>(              // qkv: N=1536, nbx=24
        xh, xl, xh,
        sWqkv, (long long)l * 786432,
        sbqkv, (size_t)l * 1536, flags,
        qkv, nullptr, nullptr, 1536, 512, 512, 24, 24, 0);
    prep_kv<<<dim3(16, 32), 256, 0, stream>>>(qkv, 1536, 512, 1024, khb, klb, vth, vtl, vcs, mmf_u);
    fattn<true><<<512, 256, 0, stream>>>(qkv, 1536, 0, khb, klb, vth, vtl, mmf_u, pvh, pvl);
    wo_term<<<64, 256, 0, stream>>>(mmf_u, vcs, sWo, (size_t)l * 262144, sbo, (size_t)l * 512,
                                    flags, term);
    gemm_bb<0, false><<<1024, 256, 0, stream>>>(            // Wo: nbx=8, split-K4
        pvh, pvl, pvh,
        sWo, (long long)l * 262144,
        sbo, 0, flags,
        pblk, nullptr, nullptr, 512, 512, 128, 8, 8, PS_FULL);
    ln_sum<4, true, true><<<ROWS, 256, 0, stream>>>(
        xf, pblk, PS_FULL, ln1g, ln1b, (size_t)l * 512, flags, mmf_u, term, xf, xh, xl);

    // ---------------- cross-attention (merged q|kv, N=1536) ----------------
    gemm_bb<0, true><<<768, 256, 0, stream>>>(              // bx<8 -> q(xh/xl); bx>=8 -> enc
        xh, xl, enc_in,
        cWqkv, (long long)l * 786432,
        cbqkv, (size_t)l * 1536, flags,
        qkv, nullptr, nullptr, 1536, 512, 512, 24, 8, 0);
    prep_kv<<<dim3(16, 32), 256, 0, stream>>>(qkv, 1536, 512, 1024, khb, klb, vth, vtl, vcs, mmf_u);
    fattn<false><<<512, 256, 0, stream>>>(qkv, 1536, 0, khb, klb, vth, vtl, mmf_u, pvh, pvl);
    wo_term<<<64, 256, 0, stream>>>(mmf_u, vcs, cWo, (size_t)l * 262144, cbo, (size_t)l * 512,
                                    flags, term);
    gemm_bb<0, false><<<1024, 256, 0, stream>>>(            // cWo: nbx=8, split-K4
        pvh, pvl, pvh,
        cWo, (long long)l * 262144,
        cbo, 0, flags,
        pblk, nullptr, nullptr, 512, 512, 128, 8, 8, PS_FULL);
    ln_sum<4, true, true><<<ROWS, 256, 0, stream>>>(
        xf, pblk, PS_FULL, ln2g, ln2b, (size_t)l * 512, flags, mmf_u, term, xf, xh, xl);

    // ---------------- FFN ----------------
    gemm_bb<1, true><<<1024, 256, 0, stream>>>(             // fc1: N=2048, nbx=32; relu->split
        xh, xl, xh,
        fc1w, (long long)l * 1048576,
        fc1b, (size_t)l * 2048, flags,
        nullptr, hh, hl, 2048, 512, 512, 32, 32, 0);
    gemm_bb<0, true><<<1024, 256, 0, stream>>>(             // fc2: nbx=8, split-K4
        hh, hl, hh,
        fc2w, (long long)l * 1048576,
        fc2b, (size_t)l * 512, flags,
        pblk, nullptr, nullptr, 512, 2048, 512, 8, 8, PS_FULL);
    if (l == 3) {
      ln_sum<4, false, false><<<ROWS, 256, 0, stream>>>(
          xf, pblk, PS_FULL, ln3g, ln3b, (size_t)l * 512, flags, nullptr, nullptr,
          (float*)d_out, nullptr, nullptr);
    } else {
      ln_sum<4, false, true><<<ROWS, 256, 0, stream>>>(
          xf, pblk, PS_FULL, ln3g, ln3b, (size_t)l * 512, flags, nullptr, nullptr,
          xf, xh, xl);
    }
  }
}

// Round 9
// 2287.595 us; speedup vs baseline: 1.4050x; 1.0050x over previous
//
#include <hip/hip_runtime.h>
#include <math.h>

typedef __bf16 bf16;
typedef unsigned short u16;
typedef unsigned int u32;
typedef __bf16 bf16x8 __attribute__((ext_vector_type(8)));
typedef float f32x4 __attribute__((ext_vector_type(4)));

#define T_SEQ 2048
#define NB    2
#define CE    512
#define HD    64
#define ROWS  4096
#define LDT   40   // GEMM LDS stride (32+8)
#define LDA   72   // attn LDS stride (64+8)

#define MFMA16(a,b,c) __builtin_amdgcn_mfma_f32_16x16x32_bf16((a),(b),(c),0,0,0)

// bijective XCD-chunked swizzle (m204)
static __device__ __forceinline__ int xcd_swz(int id, int n) {
  int q = n >> 3, r = n & 7;
  int x = id & 7, o = id >> 3;
  return (x < r) ? (x * (q + 1) + o) : (r * (q + 1) + (x - r) * q + o);
}

static __device__ __forceinline__ float ldf(const void* src, size_t eoff, bool f32) {
  return f32 ? ((const float*)src)[eoff] : (float)((const bf16*)src)[eoff];
}

// monotone float<->uint encoding for atomicMin/Max on floats
static __device__ __forceinline__ u32 fenc(float f) {
  u32 u = __float_as_uint(f);
  return (u & 0x80000000u) ? ~u : (u | 0x80000000u);
}
static __device__ __forceinline__ float fdec(u32 u) {
  u32 v = (u & 0x80000000u) ? (u & 0x7fffffffu) : ~u;
  return __uint_as_float(v);
}

// =====================================================================
// Sniffer: flags[0]=fp32 storage; flags[1]=tokens int64;
// flags[3]=enc lo nonzero (probe); flags[4]=weight lo nonzero (probe)
// =====================================================================
__global__ __launch_bounds__(256) void sniff(const u16* __restrict__ xs,
                                             const int* __restrict__ toks,
                                             int* __restrict__ flags)
{
  const int tid = threadIdx.x;
  int crazy = 0, ze = 0;
  for (int i = tid; i < 4096; i += 256) {
    int e = (xs[i] >> 7) & 0xFF;
    if (e >= 141) crazy++;
    if (((i & 1) == 0) && (xs[i] == 0)) ze++;
  }
  int zc = 0;
  for (int i = tid; i < 1024; i += 256)
    if (toks[2 * i + 1] == 0) zc++;
  __shared__ int r1[4], r2[4], r3[4];
#pragma unroll
  for (int o = 32; o; o >>= 1) {
    crazy += __shfl_down(crazy, o); ze += __shfl_down(ze, o); zc += __shfl_down(zc, o);
  }
  if ((tid & 63) == 0) { r1[tid >> 6] = crazy; r2[tid >> 6] = ze; r3[tid >> 6] = zc; }
  __syncthreads();
  if (tid == 0) {
    int c = r1[0] + r1[1] + r1[2] + r1[3];
    int z = r2[0] + r2[1] + r2[2] + r2[3];
    int t = r3[0] + r3[1] + r3[2] + r3[3];
    flags[0] = (z > 1500 || c > 64) ? 1 : 0;
    flags[1] = (t > 900) ? 1 : 0;
    flags[3] = 0;
    flags[4] = 0;
  }
}

// =====================================================================
// Read-only probe: does any weight (y<6) / enc (y==6) element have a
// nonzero bf16 low-order part? Only meaningful for fp32 storage.
// =====================================================================
__global__ __launch_bounds__(256) void probe_lo(const void* w0, const void* w1, const void* w2,
                                                const void* w3, const void* w4, const void* w5,
                                                const void* w6,
                                                int* __restrict__ flags)
{
  if (flags[0] == 0) return;       // bf16 storage: raw tensors used directly, no lo
  const int m = blockIdx.y;
  const void* srcs[7] = {w0, w1, w2, w3, w4, w5, w6};
  const int sizes[7]  = {3145728, 1048576, 3145728, 1048576, 4194304, 4194304, 2097152};
  const float4* p = (const float4*)srcs[m];
  const int n4 = sizes[m] >> 2;
  bool nz = false;
  for (int i = blockIdx.x * 256 + threadIdx.x; i < n4; i += 128 * 256) {
    float4 v = p[i];
    nz = nz || (v.x != (float)(bf16)v.x) || (v.y != (float)(bf16)v.y)
            || (v.z != (float)(bf16)v.z) || (v.w != (float)(bf16)v.w);
  }
  unsigned long long mv = __ballot(nz);
  if ((threadIdx.x & 63) == 0 && mv)
    atomicOr(&flags[(m == 6) ? 3 : 4], 1);
}

// =====================================================================
// Positional embedding: xf fp32 + xh/xl split
// =====================================================================
__global__ __launch_bounds__(256) void posembed(const void* __restrict__ xsrc,
                                                const int* __restrict__ toks,
                                                const int* __restrict__ flags,
                                                float* __restrict__ xf,
                                                bf16* __restrict__ xh, bf16* __restrict__ xl)
{
  const bool f32 = flags[0] != 0;
  const bool tok64 = flags[1] != 0;
  const int row = blockIdx.x;
  const int t = row >> 1, b = row & 1;
  const int tix = b * T_SEQ + t;
  const int tok = tok64 ? toks[2 * tix] : toks[tix];
  const int p = (tok != 0) ? (t + 1) : 0;
  const float kf = -0.0361193740f;
  for (int c = threadIdx.x; c < CE; c += 256) {
    float pe = 0.0f;
    if (p != 0) {
      int i = (c < 256) ? c : (c - 256);
      float freq = expf((float)i * kf);
      float ang = (float)p * freq;
      pe = (c < 256) ? sinf(ang) : cosf(ang);
    }
    float v = ldf(xsrc, (size_t)row * CE + c, f32) + pe;
    size_t o = (size_t)row * CE + c;
    xf[o] = v;
    bf16 hi = (bf16)v;
    xh[o] = hi; xl[o] = (bf16)(v - (float)hi);
  }
}

// =====================================================================
// MFMA GEMM, 128x64 tile, 4 waves (2Mx2N), single LDS buffer + write-late
// reg prefetch (T14), 1D grid + XCD swizzle, split-K. (unchanged from r8)
// =====================================================================
template<int OUTM, bool BIAS>
__global__ __launch_bounds__(256) void gemm_bb(const bf16* __restrict__ A1h, const bf16* __restrict__ A1l,
                                               const void* __restrict__ A2,
                                               const void* __restrict__ Braw, long long bOff,
                                               const void* __restrict__ bias, size_t biasOff,
                                               const int* __restrict__ flags,
                                               float* __restrict__ Cf,
                                               bf16* __restrict__ Coh, bf16* __restrict__ Col,
                                               int N, int K, int kspan, int nbx, int nbxA,
                                               long long partStride)
{
  __shared__ __align__(16) bf16 Ah[128 * LDT];
  __shared__ __align__(16) bf16 Al[128 * LDT];
  __shared__ __align__(16) bf16 Bh[64 * LDT];
  __shared__ __align__(16) bf16 Bl[64 * LDT];
  const int id = xcd_swz((int)blockIdx.x, (int)gridDim.x);
  const int per_z = nbx * 32;
  const int zz = id / per_z;
  const int rem = id - zz * per_z;
  const int by = rem / nbx, bx = rem - by * nbx;
  const bool bfl = flags[0] != 0;
  const bool blo = bfl && (flags[4] != 0);
  const bool aSplit = (bx < nbxA);
  const bool a2lo = bfl && (flags[3] != 0);
  const bool alo = aSplit ? true : a2lo;
  const int tid = threadIdx.x;
  const int m0 = by * 128, n0 = bx * 64;
  const int srA = tid >> 1, skA = (tid & 1) * 16;   // 128 x 32 A-slab
  const int srB = tid >> 2, skB = (tid & 3) * 8;    //  64 x 32 B-slab
  const int wid = tid >> 6, lane = tid & 63;
  const int wm = (wid >> 1) * 64, wn = (wid & 1) * 32;
  const int fr = lane & 15, fk = (lane >> 4) * 8;
  const int kb = zz * kspan;
  const int ke = (kb + kspan < K) ? (kb + kspan) : K;
  f32x4 acc[4][2] = {};

  uint4 ra0, ra1, ra2, ra3, rb0, rb1;
  auto loadA = [&](int k0) {
    size_t g = (size_t)(m0 + srA) * K + k0 + skA;
    if (aSplit) {
      const uint4* p = (const uint4*)(A1h + g); ra0 = p[0]; ra1 = p[1];
      const uint4* q = (const uint4*)(A1l + g); ra2 = q[0]; ra3 = q[1];
    } else if (bfl) {
      const uint4* p = (const uint4*)((const float*)A2 + g);
      ra0 = p[0]; ra1 = p[1]; ra2 = p[2]; ra3 = p[3];
    } else {
      const uint4* p = (const uint4*)((const bf16*)A2 + g); ra0 = p[0]; ra1 = p[1];
    }
  };
  auto loadB = [&](int k0) {
    size_t g = (size_t)bOff + (size_t)(n0 + srB) * K + k0 + skB;
    if (bfl) {
      const uint4* p = (const uint4*)((const float*)Braw + g); rb0 = p[0]; rb1 = p[1];
    } else {
      rb0 = *(const uint4*)((const bf16*)Braw + g);
    }
  };
  auto storeA = [&]() {
    if (aSplit) {
      *(uint4*)&Ah[srA * LDT + skA]     = ra0;
      *(uint4*)&Ah[srA * LDT + skA + 8] = ra1;
      *(uint4*)&Al[srA * LDT + skA]     = ra2;
      *(uint4*)&Al[srA * LDT + skA + 8] = ra3;
    } else if (bfl) {
      float v[16];
      const float* f0 = (const float*)&ra0; const float* f1 = (const float*)&ra1;
      const float* f2 = (const float*)&ra2; const float* f3 = (const float*)&ra3;
#pragma unroll
      for (int q = 0; q < 4; q++) { v[q] = f0[q]; v[4+q] = f1[q]; v[8+q] = f2[q]; v[12+q] = f3[q]; }
      bf16x8 h0, h1;
#pragma unroll
      for (int q = 0; q < 8; q++) { h0[q] = (bf16)v[q]; h1[q] = (bf16)v[8+q]; }
      *(bf16x8*)&Ah[srA * LDT + skA]     = h0;
      *(bf16x8*)&Ah[srA * LDT + skA + 8] = h1;
      if (a2lo) {
        bf16x8 l0, l1;
#pragma unroll
        for (int q = 0; q < 8; q++) {
          l0[q] = (bf16)(v[q]   - (float)h0[q]);
          l1[q] = (bf16)(v[8+q] - (float)h1[q]);
        }
        *(bf16x8*)&Al[srA * LDT + skA]     = l0;
        *(bf16x8*)&Al[srA * LDT + skA + 8] = l1;
      }
    } else {
      *(uint4*)&Ah[srA * LDT + skA]     = ra0;
      *(uint4*)&Ah[srA * LDT + skA + 8] = ra1;
    }
  };
  auto storeB = [&]() {
    if (bfl) {
      float v[8];
      const float* f0 = (const float*)&rb0; const float* f1 = (const float*)&rb1;
#pragma unroll
      for (int q = 0; q < 4; q++) { v[q] = f0[q]; v[4+q] = f1[q]; }
      bf16x8 h0;
#pragma unroll
      for (int q = 0; q < 8; q++) h0[q] = (bf16)v[q];
      *(bf16x8*)&Bh[srB * LDT + skB] = h0;
      if (blo) {
        bf16x8 l0;
#pragma unroll
        for (int q = 0; q < 8; q++) l0[q] = (bf16)(v[q] - (float)h0[q]);
        *(bf16x8*)&Bl[srB * LDT + skB] = l0;
      }
    } else {
      *(uint4*)&Bh[srB * LDT + skB] = rb0;
    }
  };

  loadA(kb); loadB(kb);
  for (int k0 = kb; k0 < ke; k0 += 32) {
    __syncthreads();                  // previous MFMA done reading LDS
    storeA(); storeB();
    __syncthreads();                  // LDS staged
    if (k0 + 32 < ke) { loadA(k0 + 32); loadB(k0 + 32); }   // rides under MFMA
    bf16x8 ah[4], bh2[2];
#pragma unroll
    for (int i = 0; i < 4; i++) ah[i] = *(const bf16x8*)&Ah[(wm + i*16 + fr) * LDT + fk];
#pragma unroll
    for (int j = 0; j < 2; j++) bh2[j] = *(const bf16x8*)&Bh[(wn + j*16 + fr) * LDT + fk];
#pragma unroll
    for (int i = 0; i < 4; i++)
#pragma unroll
      for (int j = 0; j < 2; j++)
        acc[i][j] = MFMA16(ah[i], bh2[j], acc[i][j]);
    if (alo) {
      bf16x8 al[4];
#pragma unroll
      for (int i = 0; i < 4; i++) al[i] = *(const bf16x8*)&Al[(wm + i*16 + fr) * LDT + fk];
#pragma unroll
      for (int i = 0; i < 4; i++)
#pragma unroll
        for (int j = 0; j < 2; j++)
          acc[i][j] = MFMA16(al[i], bh2[j], acc[i][j]);
    }
    if (blo) {
      bf16x8 bl[2];
#pragma unroll
      for (int j = 0; j < 2; j++) bl[j] = *(const bf16x8*)&Bl[(wn + j*16 + fr) * LDT + fk];
#pragma unroll
      for (int i = 0; i < 4; i++)
#pragma unroll
        for (int j = 0; j < 2; j++)
          acc[i][j] = MFMA16(ah[i], bl[j], acc[i][j]);
    }
  }
  const int orow0 = m0 + wm + (lane >> 4) * 4;
  const int ocol0 = n0 + wn + (lane & 15);
  if (OUTM == 0) {
    float* Cp = Cf + (long long)zz * partStride;
    const bool addb = BIAS && (zz == 0);
#pragma unroll
    for (int j = 0; j < 2; j++) {
      int col = ocol0 + j * 16;
      float bv = addb ? ldf(bias, biasOff + col, flags[0] != 0) : 0.0f;
#pragma unroll
      for (int i = 0; i < 4; i++)
#pragma unroll
        for (int r = 0; r < 4; r++)
          Cp[(size_t)(orow0 + i * 16 + r) * N + col] = acc[i][j][r] + bv;
    }
  } else {
#pragma unroll
    for (int j = 0; j < 2; j++) {
      int col = ocol0 + j * 16;
      float bv = ldf(bias, biasOff + col, flags[0] != 0);
#pragma unroll
      for (int i = 0; i < 4; i++)
#pragma unroll
        for (int r = 0; r < 4; r++) {
          float vv = fmaxf(acc[i][j][r] + bv, 0.0f);
          bf16 hi = (bf16)vv;
          size_t o = (size_t)(orow0 + i * 16 + r) * N + col;
          Coh[o] = hi; Col[o] = (bf16)(vv - (float)hi);
        }
    }
  }
}

// =====================================================================
// Fused K/V prepass + mmf init (unchanged from r8)
// =====================================================================
__global__ __launch_bounds__(256) void prep_kv(const float* __restrict__ base, int ld,
                                               int kofs0, int vofs0,
                                               bf16* __restrict__ kh, bf16* __restrict__ kl,
                                               bf16* __restrict__ vth, bf16* __restrict__ vtl,
                                               float* __restrict__ vcs,
                                               u32* __restrict__ mmf_u)
{
  __shared__ float ts[64 * 65];
  const int bh = blockIdx.x, s0 = blockIdx.y * 64;
  const int b = bh >> 3, hq = bh & 7;
  const int kofs = kofs0 + hq * HD, vofs = vofs0 + hq * HD;
  const int tid = threadIdx.x;
  if (tid == 0) { mmf_u[0] = 0xFFFFFFFFu; mmf_u[1] = 0u; }
#pragma unroll
  for (int it = 0; it < 16; ++it) {
    int idx = it * 256 + tid, r = idx >> 6, d = idx & 63;
    size_t rowb = (size_t)((s0 + r) * NB + b) * ld;
    float v = base[rowb + kofs + d];
    bf16 hi = (bf16)v;
    size_t o = ((size_t)bh * T_SEQ + s0 + r) * 64 + d;
    kh[o] = hi; kl[o] = (bf16)(v - (float)hi);
    ts[r * 65 + d] = base[rowb + vofs + d];
  }
  __syncthreads();
  const int d = tid >> 2, sseg = (tid & 3) * 16;
  bf16x8 hv0, lv0, hv1, lv1;
#pragma unroll
  for (int q = 0; q < 8; ++q) {
    float v0 = ts[(sseg + q) * 65 + d];
    float v1 = ts[(sseg + 8 + q) * 65 + d];
    bf16 h0 = (bf16)v0, h1 = (bf16)v1;
    hv0[q] = h0; lv0[q] = (bf16)(v0 - (float)h0);
    hv1[q] = h1; lv1[q] = (bf16)(v1 - (float)h1);
  }
  size_t o = ((size_t)bh * 64 + d) * T_SEQ + s0 + sseg;
  *(bf16x8*)&vth[o]     = hv0;
  *(bf16x8*)&vth[o + 8] = hv1;
  *(bf16x8*)&vtl[o]     = lv0;
  *(bf16x8*)&vtl[o + 8] = lv1;
  if (tid < 64) {
    float s = 0.0f;
    for (int j = 0; j < 64; ++j) s += ts[j * 65 + tid];
    vcs[((size_t)bh * 32 + blockIdx.y) * 64 + tid] = s;
  }
}

__device__ __forceinline__ int remap_ty(int ty) { return (ty < 16) ? ty : 47 - ty; }

// =====================================================================
// Fused attention v2: wave owns 16 t-rows x all 64 s.
//  - Q split h/l held in 4 bf16x8 REGISTERS per wave (no Q LDS).
//  - K/V next-chunk loads prefetched into regs under MFMA (T14).
//  - P tile is WAVE-PRIVATE: the QK->PV exchange needs only
//    s_waitcnt lgkmcnt(0) + sched_barrier(0), not a block barrier.
//  - 2 barriers/chunk (was 3). Numerics identical to r8 (same 3-term
//    products, same per-accumulator order) -> absmax must not move.
// =====================================================================
template<bool MASK>
__global__ __launch_bounds__(256) void fattn(const float* __restrict__ qbase, int qld, int qofs0,
                                             const bf16* __restrict__ kh, const bf16* __restrict__ kl,
                                             const bf16* __restrict__ vth, const bf16* __restrict__ vtl,
                                             u32* __restrict__ mmf_u,
                                             bf16* __restrict__ pvh, bf16* __restrict__ pvl)
{
  __shared__ __align__(16) bf16 Kh[64 * LDA], Kl[64 * LDA];
  __shared__ __align__(16) bf16 Vh[64 * LDA], Vl[64 * LDA];
  __shared__ __align__(16) bf16 Ph[64 * LDA], Pl[64 * LDA];
  __shared__ float rn[4], rx[4];
  const int id = xcd_swz((int)blockIdx.x, 512);
  const int bh = id >> 5;
  const int tyr = remap_ty(id & 31);
  const int t0 = tyr * 64;
  const int b = bh >> 3, hq = bh & 7;
  const int qofs = qofs0 + hq * HD;
  const int tid = threadIdx.x;
  const int wv = tid >> 6, lane = tid & 63;
  const int g = lane >> 4, c = lane & 15;
  // ---- Q -> registers: A-fragment layout row=c, k=g*8+q (+32ks) ----
  bf16x8 qh[2], ql[2];
  {
    size_t qrow = (size_t)((t0 + wv * 16 + c) * NB + b) * qld + qofs;
#pragma unroll
    for (int ks = 0; ks < 2; ++ks) {
      float4 f0 = *(const float4*)&qbase[qrow + ks * 32 + g * 8];
      float4 f1 = *(const float4*)&qbase[qrow + ks * 32 + g * 8 + 4];
      float v[8] = {f0.x, f0.y, f0.z, f0.w, f1.x, f1.y, f1.z, f1.w};
#pragma unroll
      for (int q = 0; q < 8; ++q) {
        float s = v[q] * 0.125f;
        bf16 hi = (bf16)s;
        qh[ks][q] = hi; ql[ks][q] = (bf16)(s - (float)hi);
      }
    }
  }
  const int cr = tid >> 2, cs = (tid & 3) * 16;
  uint4 rkh0, rkh1, rkl0, rkl1, rvh0, rvh1, rvl0, rvl1;
  auto loadKV = [&](int s0) {
    size_t go = ((size_t)bh * T_SEQ + s0 + cr) * 64 + cs;
    rkh0 = *(const uint4*)&kh[go]; rkh1 = *(const uint4*)&kh[go + 8];
    rkl0 = *(const uint4*)&kl[go]; rkl1 = *(const uint4*)&kl[go + 8];
    size_t gv = ((size_t)bh * 64 + cr) * T_SEQ + s0 + cs;
    rvh0 = *(const uint4*)&vth[gv]; rvh1 = *(const uint4*)&vth[gv + 8];
    rvl0 = *(const uint4*)&vtl[gv]; rvl1 = *(const uint4*)&vtl[gv + 8];
  };
  auto storeKV = [&]() {
    const int base = cr * LDA + cs;
    *(uint4*)&Kh[base]     = rkh0; *(uint4*)&Kh[base + 8] = rkh1;
    *(uint4*)&Kl[base]     = rkl0; *(uint4*)&Kl[base + 8] = rkl1;
    *(uint4*)&Vh[base]     = rvh0; *(uint4*)&Vh[base + 8] = rvh1;
    *(uint4*)&Vl[base]     = rvl0; *(uint4*)&Vl[base + 8] = rvl1;
  };
  float mn = 1e30f, mx = -1e30f;
  f32x4 o4[4] = {};
  const int nch = MASK ? (tyr + 1) : 32;
  loadKV(0);
  for (int sc = 0; sc < nch; ++sc) {
    const int s0 = sc * 64;
    __syncthreads();               // prior PV done reading V
    storeKV();
    __syncthreads();               // tile staged
    if (sc + 1 < nch) loadKV(s0 + 64);   // prefetch rides under QK+PV
    // ---- QK^T (3-term): out = 16t x 64s ----
    f32x4 a4[4] = {};
#pragma unroll
    for (int ks = 0; ks < 2; ++ks) {
#pragma unroll
      for (int j = 0; j < 4; ++j) {
        bf16x8 kfh = *(const bf16x8*)&Kh[(j * 16 + c) * LDA + ks * 32 + g * 8];
        bf16x8 kfl = *(const bf16x8*)&Kl[(j * 16 + c) * LDA + ks * 32 + g * 8];
        a4[j] = MFMA16(qh[ks], kfh, a4[j]);
        a4[j] = MFMA16(ql[ks], kfh, a4[j]);
        a4[j] = MFMA16(qh[ks], kfl, a4[j]);
      }
    }
    // ---- mask, min/max, wave-private P h/l ----
#pragma unroll
    for (int j = 0; j < 4; ++j)
#pragma unroll
      for (int r = 0; r < 4; ++r) {
        int tl = wv * 16 + g * 4 + r;
        int sl = j * 16 + c;
        float w = a4[j][r];
        if (MASK && (s0 + sl) > (t0 + tl)) w = 0.0f;
        mn = fminf(mn, w); mx = fmaxf(mx, w);
        bf16 wh = (bf16)w;
        Ph[tl * LDA + sl] = wh;
        Pl[tl * LDA + sl] = (bf16)(w - (float)wh);
      }
    // P is wave-private: drain DS writes, pin ordering — no block barrier
    asm volatile("s_waitcnt lgkmcnt(0)" ::: "memory");
    __builtin_amdgcn_sched_barrier(0);
    // ---- raw PV (3-term): A = P (wave's 16 t), B = V^T ----
#pragma unroll
    for (int ks = 0; ks < 2; ++ks) {
      bf16x8 pah = *(const bf16x8*)&Ph[(wv * 16 + c) * LDA + ks * 32 + g * 8];
      bf16x8 pal = *(const bf16x8*)&Pl[(wv * 16 + c) * LDA + ks * 32 + g * 8];
#pragma unroll
      for (int j = 0; j < 4; ++j) {
        bf16x8 vfh = *(const bf16x8*)&Vh[(j * 16 + c) * LDA + ks * 32 + g * 8];
        bf16x8 vfl = *(const bf16x8*)&Vl[(j * 16 + c) * LDA + ks * 32 + g * 8];
        o4[j] = MFMA16(pah, vfh, o4[j]);
        o4[j] = MFMA16(pal, vfh, o4[j]);
        o4[j] = MFMA16(pah, vfl, o4[j]);
      }
    }
  }
  // ---- write raw PV, split h/l ----
#pragma unroll
  for (int j = 0; j < 4; ++j)
#pragma unroll
    for (int r = 0; r < 4; ++r) {
      int tl = wv * 16 + g * 4 + r;
      int dl = j * 16 + c;
      float val = o4[j][r];
      bf16 hi = (bf16)val;
      size_t o = (size_t)((t0 + tl) * NB + b) * CE + hq * HD + dl;
      pvh[o] = hi; pvl[o] = (bf16)(val - (float)hi);
    }
  // ---- global min/max via encoded atomics ----
#pragma unroll
  for (int o = 32; o; o >>= 1) { mn = fminf(mn, __shfl_down(mn, o)); mx = fmaxf(mx, __shfl_down(mx, o)); }
  if (lane == 0) { rn[wv] = mn; rx[wv] = mx; }
  __syncthreads();
  if (tid == 0) {
    float bmn = fminf(fminf(rn[0], rn[1]), fminf(rn[2], rn[3]));
    float bmx = fmaxf(fmaxf(rx[0], rx[1]), fmaxf(rx[2], rx[3]));
    atomicMin(&mmf_u[0], fenc(bmn));
    atomicMax(&mmf_u[1], fenc(bmx));
  }
}

// =====================================================================
// term[b*512+c] = -(mn*inv)*(vsum[b]@Wo[c]) + bo[c] (unchanged from r8)
// =====================================================================
__global__ __launch_bounds__(256) void wo_term(const u32* __restrict__ mmf_u,
                                               const float* __restrict__ vcs,
                                               const void* __restrict__ Wo, size_t woOff,
                                               const void* __restrict__ bo, size_t boOff,
                                               const int* __restrict__ flags,
                                               float* __restrict__ term)
{
  __shared__ float vs[512];
  const bool fl = flags[0] != 0;
  const int tid = threadIdx.x;
  const float mn = fdec(mmf_u[0]);
  const float inv = 1.0f / (fdec(mmf_u[1]) - mn);
  const float cmn = mn * inv;
  const int b = blockIdx.x >> 5;
  for (int k = tid; k < 512; k += 256) {
    int h = k >> 6, d = k & 63;
    float s = 0.0f;
#pragma unroll
    for (int ch = 0; ch < 32; ++ch)
      s += vcs[(size_t)((b * 8 + h) * 32 + ch) * 64 + d];
    vs[k] = s;
  }
  __syncthreads();
  const int out = blockIdx.x * 16 + (tid >> 4);
  const int c = out & 511;
  const int k0 = (tid & 15) * 32;
  float s = 0.0f;
#pragma unroll 8
  for (int k = 0; k < 32; ++k)
    s += vs[k0 + k] * ldf(Wo, woOff + (size_t)c * 512 + k0 + k, fl);
  s += __shfl_down(s, 8); s += __shfl_down(s, 4); s += __shfl_down(s, 2); s += __shfl_down(s, 1);
  if ((tid & 15) == 0)
    term[out] = -cmn * s + ldf(bo, boOff + c, fl);
}

// =====================================================================
// LayerNorm(res + [AFF? inv*sum(NP partials)+term : sum(NP partials)])
// =====================================================================
template<int NP, bool AFF, bool SPLIT>
__global__ __launch_bounds__(256) void ln_sum(const float* __restrict__ res,
                                              const float* __restrict__ p, long long pstride,
                                              const void* __restrict__ g, const void* __restrict__ be,
                                              size_t goff, const int* __restrict__ flags,
                                              const u32* __restrict__ mmf_u,
                                              const float* __restrict__ term,
                                              float* __restrict__ xfo,
                                              bf16* __restrict__ xh, bf16* __restrict__ xl)
{
  __shared__ float red[4];
  const bool fl = flags[0] != 0;
  const int tid = threadIdx.x;
  const size_t base = (size_t)blockIdx.x * CE;
  float pa = 0.0f, pb = 0.0f;
#pragma unroll
  for (int k = 0; k < NP; k++) {
    pa += p[(long long)k * pstride + base + tid];
    pb += p[(long long)k * pstride + base + tid + 256];
  }
  float a, b2;
  if (AFF) {
    const float mnv = fdec(mmf_u[0]);
    const float inv = 1.0f / (fdec(mmf_u[1]) - mnv);
    const int b = blockIdx.x & 1;
    a  = res[base + tid]       + inv * pa + term[b * 512 + tid];
    b2 = res[base + tid + 256] + inv * pb + term[b * 512 + tid + 256];
  } else {
    a  = res[base + tid]       + pa;
    b2 = res[base + tid + 256] + pb;
  }
  float s = a + b2;
#pragma unroll
  for (int o = 32; o; o >>= 1) s += __shfl_down(s, o);
  if ((tid & 63) == 0) red[tid >> 6] = s;
  __syncthreads();
  float mu = (red[0] + red[1] + red[2] + red[3]) * (1.0f / 512.0f);
  __syncthreads();
  float da = a - mu, db = b2 - mu;
  float q = da * da + db * db;
#pragma unroll
  for (int o = 32; o; o >>= 1) q += __shfl_down(q, o);
  if ((tid & 63) == 0) red[tid >> 6] = q;
  __syncthreads();
  float var = (red[0] + red[1] + red[2] + red[3]) * (1.0f / 512.0f);
  float rs = rsqrtf(var + 1e-20f);
  float o1 = da * rs * ldf(g, goff + tid, fl)       + ldf(be, goff + tid, fl);
  float o2 = db * rs * ldf(g, goff + tid + 256, fl) + ldf(be, goff + tid + 256, fl);
  xfo[base + tid]       = o1;
  xfo[base + tid + 256] = o2;
  if (SPLIT) {
    bf16 h1 = (bf16)o1, h2 = (bf16)o2;
    xh[base + tid]       = h1; xl[base + tid]       = (bf16)(o1 - (float)h1);
    xh[base + tid + 256] = h2; xl[base + tid + 256] = (bf16)(o2 - (float)h2);
  }
}

// =====================================================================
extern "C" void kernel_launch(void* const* d_in, const int* in_sizes, int n_in,
                              void* d_out, int out_size, void* d_ws, size_t ws_size,
                              hipStream_t stream)
{
  (void)in_sizes; (void)n_in; (void)out_size; (void)ws_size;
  const void* x_in   = d_in[0];
  const void* enc_in = d_in[1];
  const int*  tokens = (const int*)d_in[2];
  const void* sWqkv = d_in[3];
  const void* sbqkv = d_in[4];
  const void* sWo   = d_in[5];
  const void* sbo   = d_in[6];
  const void* cWqkv = d_in[7];
  const void* cbqkv = d_in[8];
  const void* cWo   = d_in[9];
  const void* cbo   = d_in[10];
  const void* fc1w  = d_in[11];
  const void* fc1b  = d_in[12];
  const void* fc2w  = d_in[13];
  const void* fc2b  = d_in[14];
  const void* ln1g  = d_in[15];
  const void* ln1b  = d_in[16];
  const void* ln2g  = d_in[17];
  const void* ln2b  = d_in[18];
  const void* ln3g  = d_in[19];
  const void* ln3b  = d_in[20];

  char* ws = (char*)d_ws;
  size_t off = 0;
  auto alloc = [&](size_t bytes) -> char* {
    char* p = ws + off;
    off += (bytes + 255) & ~(size_t)255;
    return p;
  };
  int*   flags   = (int*)  alloc(256);
  u32*   mmf_u   = (u32*)  alloc(256);
  float* term    = (float*)alloc(1024 * 4);
  float* xf      = (float*)alloc((size_t)ROWS * CE * 4);          //  8 MiB residual
  bf16*  xh      = (bf16*) alloc((size_t)ROWS * CE * 2);          //  4 MiB
  bf16*  xl      = (bf16*) alloc((size_t)ROWS * CE * 2);          //  4 MiB
  float* qkv     = (float*)alloc((size_t)ROWS * 2048 * 4);        // 32 MiB (proj fp32 / h split)
  bf16*  pvh     = (bf16*) alloc((size_t)ROWS * CE * 2);          //  4 MiB
  bf16*  pvl     = (bf16*) alloc((size_t)ROWS * CE * 2);          //  4 MiB
  float* pblk    = (float*)alloc((size_t)ROWS * CE * 4 * 4);      // 32 MiB split-K partials
  bf16*  khb     = (bf16*) alloc((size_t)16 * T_SEQ * 64 * 2);    //  4 MiB
  bf16*  klb     = (bf16*) alloc((size_t)16 * T_SEQ * 64 * 2);    //  4 MiB
  bf16*  vth     = (bf16*) alloc((size_t)16 * 64 * T_SEQ * 2);    //  4 MiB
  bf16*  vtl     = (bf16*) alloc((size_t)16 * 64 * T_SEQ * 2);    //  4 MiB
  float* vcs     = (float*)alloc((size_t)16 * 32 * 64 * 4);       // 128 KiB
  bf16* hh = (bf16*)qkv;                     // h split aliases qkv
  bf16* hl = (bf16*)qkv + (size_t)ROWS * 2048;
  const long long PS_FULL = (long long)ROWS * CE;

  sniff<<<1, 256, 0, stream>>>((const u16*)x_in, tokens, flags);
  probe_lo<<<dim3(128, 7), 256, 0, stream>>>(sWqkv, sWo, cWqkv, cWo, fc1w, fc2w, enc_in, flags);
  posembed<<<ROWS, 256, 0, stream>>>(x_in, tokens, flags, xf, xh, xl);

  for (int l = 0; l < 4; l++) {
    // ---------------- self-attention ----------------
    gemm_bb<0, true><<<768, 256, 0, stream>>>(              // qkv: N=1536, nbx=24
        xh, xl, xh,
        sWqkv, (long long)l * 786432,
        sbqkv, (size_t)l * 1536, flags,
        qkv, nullptr, nullptr, 1536, 512, 512, 24, 24, 0);
    prep_kv<<<dim3(16, 32), 256, 0, stream>>>(qkv, 1536, 512, 1024, khb, klb, vth, vtl, vcs, mmf_u);
    fattn<true><<<512, 256, 0, stream>>>(qkv, 1536, 0, khb, klb, vth, vtl, mmf_u, pvh, pvl);
    wo_term<<<64, 256, 0, stream>>>(mmf_u, vcs, sWo, (size_t)l * 262144, sbo, (size_t)l * 512,
                                    flags, term);
    gemm_bb<0, false><<<1024, 256, 0, stream>>>(            // Wo: nbx=8, split-K4
        pvh, pvl, pvh,
        sWo, (long long)l * 262144,
        sbo, 0, flags,
        pblk, nullptr, nullptr, 512, 512, 128, 8, 8, PS_FULL);
    ln_sum<4, true, true><<<ROWS, 256, 0, stream>>>(
        xf, pblk, PS_FULL, ln1g, ln1b, (size_t)l * 512, flags, mmf_u, term, xf, xh, xl);

    // ---------------- cross-attention (merged q|kv, N=1536) ----------------
    gemm_bb<0, true><<<768, 256, 0, stream>>>(              // bx<8 -> q(xh/xl); bx>=8 -> enc
        xh, xl, enc_in,
        cWqkv, (long long)l * 786432,
        cbqkv, (size_t)l * 1536, flags,
        qkv, nullptr, nullptr, 1536, 512, 512, 24, 8, 0);
    prep_kv<<<dim3(16, 32), 256, 0, stream>>>(qkv, 1536, 512, 1024, khb, klb, vth, vtl, vcs, mmf_u);
    fattn<false><<<512, 256, 0, stream>>>(qkv, 1536, 0, khb, klb, vth, vtl, mmf_u, pvh, pvl);
    wo_term<<<64, 256, 0, stream>>>(mmf_u, vcs, cWo, (size_t)l * 262144, cbo, (size_t)l * 512,
                                    flags, term);
    gemm_bb<0, false><<<1024, 256, 0, stream>>>(            // cWo: nbx=8, split-K4
        pvh, pvl, pvh,
        cWo, (long long)l * 262144,
        cbo, 0, flags,
        pblk, nullptr, nullptr, 512, 512, 128, 8, 8, PS_FULL);
    ln_sum<4, true, true><<<ROWS, 256, 0, stream>>>(
        xf, pblk, PS_FULL, ln2g, ln2b, (size_t)l * 512, flags, mmf_u, term, xf, xh, xl);

    // ---------------- FFN ----------------
    gemm_bb<1, true><<<1024, 256, 0, stream>>>(             // fc1: N=2048, nbx=32; relu->split
        xh, xl, xh,
        fc1w, (long long)l * 1048576,
        fc1b, (size_t)l * 2048, flags,
        nullptr, hh, hl, 2048, 512, 512, 32, 32, 0);
    gemm_bb<0, true><<<1024, 256, 0, stream>>>(             // fc2: nbx=8, split-K4
        hh, hl, hh,
        fc2w, (long long)l * 1048576,
        fc2b, (size_t)l * 512, flags,
        pblk, nullptr, nullptr, 512, 2048, 512, 8, 8, PS_FULL);
    if (l == 3) {
      ln_sum<4, false, false><<<ROWS, 256, 0, stream>>>(
          xf, pblk, PS_FULL, ln3g, ln3b, (size_t)l * 512, flags, nullptr, nullptr,
          (float*)d_out, nullptr, nullptr);
    } else {
      ln_sum<4, false, true><<<ROWS, 256, 0, stream>>>(
          xf, pblk, PS_FULL, ln3g, ln3b, (size_t)l * 512, flags, nullptr, nullptr,
          xf, xh, xl);
    }
  }
}